// Round 6
// baseline (1391.814 us; speedup 1.0000x reference)
//
#include <hip/hip_runtime.h>

#define NN 8192
#define HH 64
constexpr float LALPHA = 0.2f;

typedef __attribute__((ext_vector_type(8))) short bf16x8;
typedef __attribute__((ext_vector_type(4))) float f32x4;

__device__ inline short f2bf(float f) {
  unsigned u = __builtin_bit_cast(unsigned, f);
  u += 0x7FFFu + ((u >> 16) & 1u);
  return (short)(u >> 16);
}

// ---------------------------------------------------------------- prep: ht transpose + diag + column-sum partials
__global__ __launch_bounds__(256) void k_prep(const float* __restrict__ h,
                                              const float* __restrict__ na,
                                              const float* __restrict__ ea,
                                              unsigned short* __restrict__ ht,
                                              float* __restrict__ dn,
                                              float* __restrict__ de,
                                              float* __restrict__ HbP) {
  __shared__ float tile[64][65];
  const int j0 = blockIdx.x * 64;
  for (int l = threadIdx.x; l < 64 * 64; l += 256) {
    int r = l >> 6, c = l & 63;
    tile[r][c] = h[(size_t)(j0 + r) * HH + c];
  }
  __syncthreads();
  for (int l = threadIdx.x; l < 64 * 64; l += 256) {
    int c = l >> 6, r = l & 63;
    ht[(size_t)c * NN + j0 + r] = (unsigned short)f2bf(tile[r][c]);
  }
  const int t = threadIdx.x;
  if (t < 64) {  // column sums of this band
    float s = 0.f;
    for (int r = 0; r < 64; ++r) s += tile[r][t];
    HbP[blockIdx.x * 64 + t] = s;
  } else if (t < 128) {  // diagonal extract
    int i = j0 + (t - 64);
    dn[i] = na[(size_t)i * NN + i];
    de[i] = ea[(size_t)i * NN + i];
  }
}

__global__ __launch_bounds__(64) void k_hbarF(const float* __restrict__ HbP,
                                              float* __restrict__ Hb) {
  int c = threadIdx.x;
  float s = 0.f;
  for (int b = 0; b < 128; ++b) s += HbP[b * 64 + c];
  Hb[c] = s;
}

// ---------------------------------------------------------------- heavy masked matmuls via MFMA
// r2-proven register path; KS=16 -> 2048 blocks -> 8 blocks/CU -> 32 waves/CU.
template <int KS>
__global__ __launch_bounds__(256, 8) void k_stageA(
    const float* __restrict__ na, const float* __restrict__ ea,
    const unsigned short* __restrict__ ht,
    float* __restrict__ SpP, float* __restrict__ TfP,
    float* __restrict__ TpP, float* __restrict__ cpP) {
  const int lane  = threadIdx.x & 63;
  const int wid   = threadIdx.x >> 6;
  const int row16 = lane & 15;
  const int kgrp  = lane >> 4;
  const int i0    = blockIdx.x * 64 + wid * 16;
  const int ks    = blockIdx.y;
  const int kbeg  = ks * (NN / KS);

  f32x4 accS[4] = {}, accF[4] = {}, accP[4] = {};
  float cnt = 0.f;

  const float* naRow = na + (size_t)(i0 + row16) * NN;
  const float* eaRow = ea + (size_t)(i0 + row16) * NN;

  for (int k0 = kbeg; k0 < kbeg + NN / KS; k0 += 32) {
    const int kk = k0 + kgrp * 8;
    const float4 a0 = *reinterpret_cast<const float4*>(naRow + kk);
    const float4 a1 = *reinterpret_cast<const float4*>(naRow + kk + 4);
    const float4 e0 = *reinterpret_cast<const float4*>(eaRow + kk);
    const float4 e1 = *reinterpret_cast<const float4*>(eaRow + kk + 4);
    const float av[8] = {a0.x, a0.y, a0.z, a0.w, a1.x, a1.y, a1.z, a1.w};
    const float ev[8] = {e0.x, e0.y, e0.z, e0.w, e1.x, e1.y, e1.z, e1.w};
    bf16x8 fS, fF, fP;
#pragma unroll
    for (int q = 0; q < 8; ++q) {
      fS[q] = (av[q] > 0.f) ? (short)0x3F80 : (short)0;
      fF[q] = f2bf(ev[q]);
      fP[q] = f2bf(fmaxf(ev[q], 0.f));
      cnt += (ev[q] > 0.f) ? 1.f : 0.f;
    }
#pragma unroll
    for (int c = 0; c < 4; ++c) {
      const bf16x8 fB = *reinterpret_cast<const bf16x8*>(
          ht + (size_t)(c * 16 + row16) * NN + kk);
      accS[c] = __builtin_amdgcn_mfma_f32_16x16x32_bf16(fS, fB, accS[c], 0, 0, 0);
      accF[c] = __builtin_amdgcn_mfma_f32_16x16x32_bf16(fF, fB, accF[c], 0, 0, 0);
      accP[c] = __builtin_amdgcn_mfma_f32_16x16x32_bf16(fP, fB, accP[c], 0, 0, 0);
    }
  }
  cnt += __shfl_xor(cnt, 16);
  cnt += __shfl_xor(cnt, 32);
  if (lane < 16) cpP[ks * NN + i0 + lane] = cnt;

  const size_t base = (size_t)ks * ((size_t)NN * HH);
#pragma unroll
  for (int c = 0; c < 4; ++c) {
#pragma unroll
    for (int r = 0; r < 4; ++r) {
      const int row = i0 + kgrp * 4 + r;
      const int col = c * 16 + row16;
      const size_t idx = base + (size_t)row * HH + col;
      SpP[idx] = accS[c][r];
      TfP[idx] = accF[c][r];
      TpP[idx] = accP[c][r];
    }
  }
}

// ---------------------------------------------------------------- fused epilogue
// Per 16-row block: combine partials -> Sp,Sm,Tp,Tm -> HP/HM=Sp/Sm@W ->
// analytic GAT -> U -> ES=U@W -> GRU-edge([Sp|Sm]) -> GRU-node(ES) -> out.
template <int KS>
__global__ __launch_bounds__(256) void k_epi(
    const float* __restrict__ h, const float* __restrict__ dn_g,
    const float* __restrict__ de_g, const float* __restrict__ Hb,
    const float* __restrict__ SpP, const float* __restrict__ TfP,
    const float* __restrict__ TpP, const float* __restrict__ cpP,
    const float* __restrict__ Wg, const float* __restrict__ ag,
    const float* __restrict__ wihe, const float* __restrict__ whhe,
    const float* __restrict__ bihe, const float* __restrict__ bhhe,
    const float* __restrict__ wihn, const float* __restrict__ whhn,
    const float* __restrict__ bihn, const float* __restrict__ bhhn,
    float* __restrict__ out) {
  __shared__ float sW[64][64];
  __shared__ float sSp[16][64], sSm[16][64], sTp[16][64], sTm[16][64], sh[16][64];
  __shared__ float sX1[16][64], sX2[16][64];
  __shared__ float swt[192][33];
  __shared__ float sag[128], sHb[64];
  __shared__ float swp[16], swm[16], sdn[16], sde[16], scp[16];
  const int t = threadIdx.x;
  const int i0 = blockIdx.x * 16;
  const size_t SZ = (size_t)NN * HH;

  for (int l = t; l < 4096; l += 256) sW[l >> 6][l & 63] = Wg[l];
  if (t < 128) sag[t] = ag[t];
  if (t < 64) sHb[t] = Hb[t];
  if (t < 16) { sdn[t] = dn_g[i0 + t]; sde[t] = de_g[i0 + t]; }

  // ---- P1: sum partials (vectorized), diag-correct, stash in LDS
  const int e0 = t * 4;                 // 0..1020, 4 elems/thread
  const int r1 = e0 >> 6, c1 = e0 & 63;
  const size_t gbase = (size_t)i0 * 64 + e0;
  float4 sp4 = {0, 0, 0, 0}, tf4 = {0, 0, 0, 0}, tp4 = {0, 0, 0, 0};
#pragma unroll
  for (int s = 0; s < KS; ++s) {
    const float4 a = *reinterpret_cast<const float4*>(&SpP[s * SZ + gbase]);
    const float4 b = *reinterpret_cast<const float4*>(&TfP[s * SZ + gbase]);
    const float4 c = *reinterpret_cast<const float4*>(&TpP[s * SZ + gbase]);
    sp4.x += a.x; sp4.y += a.y; sp4.z += a.z; sp4.w += a.w;
    tf4.x += b.x; tf4.y += b.y; tf4.z += b.z; tf4.w += b.w;
    tp4.x += c.x; tp4.y += c.y; tp4.z += c.z; tp4.w += c.w;
  }
  const float4 h4 = *reinterpret_cast<const float4*>(&h[gbase]);
  float cnt1 = 0.f;
  if (t < 16) {
    for (int s = 0; s < KS; ++s) cnt1 += cpP[s * NN + i0 + t];
  }
  __syncthreads();  // sdn/sde/sHb ready
  {
    const float dni = sdn[r1], dei = sde[r1];
    const float hv[4] = {h4.x, h4.y, h4.z, h4.w};
    const float spv[4] = {sp4.x, sp4.y, sp4.z, sp4.w};
    const float tfv[4] = {tf4.x, tf4.y, tf4.z, tf4.w};
    const float tpv[4] = {tp4.x, tp4.y, tp4.z, tp4.w};
#pragma unroll
    for (int q = 0; q < 4; ++q) {
      const int c = c1 + q;
      float sp = spv[q] - ((dni > 0.f) ? hv[q] : 0.f);
      float tf = tfv[q] - dei * hv[q];
      float tp = tpv[q] - fmaxf(dei, 0.f) * hv[q];
      sSp[r1][c] = sp;
      sSm[r1][c] = sHb[c] - hv[q] - sp;
      sTp[r1][c] = tp;
      sTm[r1][c] = tf - tp;
      sh[r1][c] = hv[q];
    }
    if (t < 16) scp[t] = cnt1 - ((sde[t] > 0.f) ? 1.f : 0.f);
  }
  __syncthreads();

  // ---- P2: HP = Sp@W, HM = Sm@W
  const int w4 = t >> 6, cc = t & 63;
#pragma unroll
  for (int j = 0; j < 4; ++j) {
    const int r = 4 * w4 + j;
    float hp = 0.f, hm = 0.f;
    for (int k = 0; k < 64; ++k) {
      const float wv = sW[k][cc];
      hp += sSp[r][k] * wv;
      hm += sSm[r][k] * wv;
    }
    sX1[r][cc] = hp;
    sX2[r][cc] = hm;
  }
  __syncthreads();

  // ---- P3: analytic GAT softmax weights per row
  if (t < 16) {
    float ep = 0.f, em = 0.f;
    for (int c = 0; c < 64; ++c) {
      const float hp = sX1[t][c], hm = sX2[t][c];
      ep += hp * sag[c] + hm * sag[64 + c];
      em += hm * sag[c] + hp * sag[64 + c];
    }
    ep = ep > 0.f ? ep : LALPHA * ep;
    em = em > 0.f ? em : LALPHA * em;
    const float cp = scp[t];
    const float cm = (float)(NN - 1) - cp;
    const float NEGI = -3.0e38f;
    const float m = fmaxf(cp > 0.f ? ep : NEGI, cm > 0.f ? em : NEGI);
    const float xp = (cp > 0.f) ? expf(ep - m) : 0.f;
    const float xm = (cm > 0.f) ? expf(em - m) : 0.f;
    const float denom = cp * xp + cm * xm;
    const float inv = denom > 0.f ? 1.f / denom : 0.f;
    swp[t] = xp * inv;
    swm[t] = xm * inv;
  }
  __syncthreads();

  // ---- P4: U = wp*Tp + wm*Tm (into sTp)
#pragma unroll
  for (int q = 0; q < 4; ++q) {
    const int c = c1 + q;
    sTp[r1][c] = swp[r1] * sTp[r1][c] + swm[r1] * sTm[r1][c];
  }
  __syncthreads();

  // ---- P5: ES = U@W (into sX2)
#pragma unroll
  for (int j = 0; j < 4; ++j) {
    const int r = 4 * w4 + j;
    float es = 0.f;
    for (int k = 0; k < 64; ++k) es += sTp[r][k] * sW[k][cc];
    sX2[r][cc] = es;
  }
  // (sync happens inside first weight-stage below)

  // ---- P6: GRU-edge, x=[Sp|Sm] (K=128), out EO -> sX1
  {
    float gi[3][4] = {}, gh[3][4] = {};
#pragma unroll
    for (int ch = 0; ch < 4; ++ch) {  // wihe: 4 chunks of 32 k
      __syncthreads();
      for (int l = t; l < 6144; l += 256)
        swt[l >> 5][l & 31] = wihe[(size_t)(l >> 5) * 128 + ch * 32 + (l & 31)];
      __syncthreads();
#pragma unroll
      for (int j = 0; j < 4; ++j) {
        const int r = 4 * w4 + j;
        for (int kk = 0; kk < 32; ++kk) {
          const float xk = (ch < 2) ? sSp[r][ch * 32 + kk] : sSm[r][(ch - 2) * 32 + kk];
          gi[0][j] += xk * swt[cc][kk];
          gi[1][j] += xk * swt[64 + cc][kk];
          gi[2][j] += xk * swt[128 + cc][kk];
        }
      }
    }
#pragma unroll
    for (int ch = 0; ch < 2; ++ch) {  // whhe: 2 chunks of 32 k
      __syncthreads();
      for (int l = t; l < 6144; l += 256)
        swt[l >> 5][l & 31] = whhe[(size_t)(l >> 5) * 64 + ch * 32 + (l & 31)];
      __syncthreads();
#pragma unroll
      for (int j = 0; j < 4; ++j) {
        const int r = 4 * w4 + j;
        for (int kk = 0; kk < 32; ++kk) {
          const float hk = sh[r][ch * 32 + kk];
          gh[0][j] += hk * swt[cc][kk];
          gh[1][j] += hk * swt[64 + cc][kk];
          gh[2][j] += hk * swt[128 + cc][kk];
        }
      }
    }
    const float br = bihe[cc], bz = bihe[64 + cc], bn = bihe[128 + cc];
    const float dr = bhhe[cc], dz = bhhe[64 + cc], dnb = bhhe[128 + cc];
#pragma unroll
    for (int j = 0; j < 4; ++j) {
      const int r = 4 * w4 + j;
      const float rg = 1.f / (1.f + expf(-(gi[0][j] + br + gh[0][j] + dr)));
      const float zg = 1.f / (1.f + expf(-(gi[1][j] + bz + gh[1][j] + dz)));
      const float ng = tanhf(gi[2][j] + bn + rg * (gh[2][j] + dnb));
      sX1[r][cc] = (1.f - zg) * ng + zg * sh[r][cc];
    }
  }

  // ---- P7: GRU-node, x=ES (K=64), combine with EO -> out
  {
    float gi[3][4] = {}, gh[3][4] = {};
#pragma unroll
    for (int ch = 0; ch < 2; ++ch) {  // wihn: 2 chunks of 32 k
      __syncthreads();
      for (int l = t; l < 6144; l += 256)
        swt[l >> 5][l & 31] = wihn[(size_t)(l >> 5) * 64 + ch * 32 + (l & 31)];
      __syncthreads();
#pragma unroll
      for (int j = 0; j < 4; ++j) {
        const int r = 4 * w4 + j;
        for (int kk = 0; kk < 32; ++kk) {
          const float xk = sX2[r][ch * 32 + kk];
          gi[0][j] += xk * swt[cc][kk];
          gi[1][j] += xk * swt[64 + cc][kk];
          gi[2][j] += xk * swt[128 + cc][kk];
        }
      }
    }
#pragma unroll
    for (int ch = 0; ch < 2; ++ch) {  // whhn: 2 chunks of 32 k
      __syncthreads();
      for (int l = t; l < 6144; l += 256)
        swt[l >> 5][l & 31] = whhn[(size_t)(l >> 5) * 64 + ch * 32 + (l & 31)];
      __syncthreads();
#pragma unroll
      for (int j = 0; j < 4; ++j) {
        const int r = 4 * w4 + j;
        for (int kk = 0; kk < 32; ++kk) {
          const float hk = sh[r][ch * 32 + kk];
          gh[0][j] += hk * swt[cc][kk];
          gh[1][j] += hk * swt[64 + cc][kk];
          gh[2][j] += hk * swt[128 + cc][kk];
        }
      }
    }
    const float br = bihn[cc], bz = bihn[64 + cc], bn = bihn[128 + cc];
    const float dr = bhhn[cc], dz = bhhn[64 + cc], dnb = bhhn[128 + cc];
#pragma unroll
    for (int j = 0; j < 4; ++j) {
      const int r = 4 * w4 + j;
      const float rg = 1.f / (1.f + expf(-(gi[0][j] + br + gh[0][j] + dr)));
      const float zg = 1.f / (1.f + expf(-(gi[1][j] + bz + gh[1][j] + dz)));
      const float ng = tanhf(gi[2][j] + bn + rg * (gh[2][j] + dnb));
      const float no = (1.f - zg) * ng + zg * sh[r][cc];
      out[(size_t)(i0 + r) * 64 + cc] = sde[r] * sX1[r][cc] + sdn[r] * no;
    }
  }
}

// ---------------------------------------------------------------- launch
template <int KS>
static void launch_all(const float* h, const float* na, const float* ea,
                       const float* Wg, const float* ag, const float* wihe,
                       const float* whhe, const float* bihe, const float* bhhe,
                       const float* wihn, const float* whhn, const float* bihn,
                       const float* bhhn, float* out, float* ws,
                       hipStream_t stream) {
  const size_t SZ = (size_t)NN * HH;
  float* SpP = ws;
  float* TfP = ws + (size_t)KS * SZ;
  float* TpP = ws + (size_t)2 * KS * SZ;
  float* cpP = ws + (size_t)3 * KS * SZ;       // KS*NN
  float* dn  = cpP + (size_t)KS * NN;          // NN
  float* de  = dn + NN;                        // NN
  float* HbP = de + NN;                        // 128*64
  float* Hb  = HbP + 128 * 64;                 // 64
  unsigned short* ht = (unsigned short*)(Hb + 64);

  k_prep<<<NN / 64, 256, 0, stream>>>(h, na, ea, ht, dn, de, HbP);
  k_hbarF<<<1, 64, 0, stream>>>(HbP, Hb);
  k_stageA<KS><<<dim3(NN / 64, KS), 256, 0, stream>>>(na, ea, ht, SpP, TfP, TpP, cpP);
  k_epi<KS><<<NN / 16, 256, 0, stream>>>(h, dn, de, Hb, SpP, TfP, TpP, cpP,
                                         Wg, ag, wihe, whhe, bihe, bhhe,
                                         wihn, whhn, bihn, bhhn, out);
}

extern "C" void kernel_launch(void* const* d_in, const int* in_sizes, int n_in,
                              void* d_out, int out_size, void* d_ws, size_t ws_size,
                              hipStream_t stream) {
  const float* h    = (const float*)d_in[0];
  const float* na   = (const float*)d_in[1];
  const float* ea   = (const float*)d_in[2];
  const float* Wg   = (const float*)d_in[3];
  const float* ag   = (const float*)d_in[4];
  const float* wihe = (const float*)d_in[5];
  const float* whhe = (const float*)d_in[6];
  const float* bihe = (const float*)d_in[7];
  const float* bhhe = (const float*)d_in[8];
  const float* wihn = (const float*)d_in[9];
  const float* whhn = (const float*)d_in[10];
  const float* bihn = (const float*)d_in[11];
  const float* bhhn = (const float*)d_in[12];
  float* out = (float*)d_out;
  float* ws  = (float*)d_ws;

  const size_t SZ = (size_t)NN * HH;
  auto need = [&](int ks) {
    return (3 * (size_t)ks * SZ + (size_t)ks * NN + 2 * NN + 128 * 64 + 64) * 4 +
           (size_t)NN * HH * 2;
  };
  if (ws_size >= need(16)) {
    launch_all<16>(h, na, ea, Wg, ag, wihe, whhe, bihe, bhhe, wihn, whhn,
                   bihn, bhhn, out, ws, stream);
  } else if (ws_size >= need(8)) {
    launch_all<8>(h, na, ea, Wg, ag, wihe, whhe, bihe, bhhe, wihn, whhn,
                  bihn, bhhn, out, ws, stream);
  } else {
    launch_all<4>(h, na, ea, Wg, ag, wihe, whhe, bihe, bhhe, wihn, whhn,
                  bihn, bhhn, out, ws, stream);
  }
}

// Round 7
// 312.180 us; speedup vs baseline: 4.4584x; 4.4584x over previous
//
#include <hip/hip_runtime.h>

#define NN 8192
#define HH 64
constexpr float LALPHA = 0.2f;

typedef __attribute__((ext_vector_type(8))) short bf16x8;
typedef __attribute__((ext_vector_type(4))) float f32x4;

__device__ inline short f2bf(float f) {
  unsigned u = __builtin_bit_cast(unsigned, f);
  u += 0x7FFFu + ((u >> 16) & 1u);
  return (short)(u >> 16);
}

// ---------------------------------------------------------------- prep: ht transpose + diag + column-sum partials
__global__ __launch_bounds__(256) void k_prep(const float* __restrict__ h,
                                              const float* __restrict__ na,
                                              const float* __restrict__ ea,
                                              unsigned short* __restrict__ ht,
                                              float* __restrict__ dn,
                                              float* __restrict__ de,
                                              float* __restrict__ HbP) {
  __shared__ float tile[64][65];
  const int j0 = blockIdx.x * 64;
  for (int l = threadIdx.x; l < 64 * 64; l += 256) {
    int r = l >> 6, c = l & 63;
    tile[r][c] = h[(size_t)(j0 + r) * HH + c];
  }
  __syncthreads();
  for (int l = threadIdx.x; l < 64 * 64; l += 256) {
    int c = l >> 6, r = l & 63;
    ht[(size_t)c * NN + j0 + r] = (unsigned short)f2bf(tile[r][c]);
  }
  const int t = threadIdx.x;
  if (t < 64) {
    float s = 0.f;
    for (int r = 0; r < 64; ++r) s += tile[r][t];
    HbP[blockIdx.x * 64 + t] = s;
  } else if (t < 128) {
    int i = j0 + (t - 64);
    dn[i] = na[(size_t)i * NN + i];
    de[i] = ea[(size_t)i * NN + i];
  }
}

__global__ __launch_bounds__(64) void k_hbarF(const float* __restrict__ HbP,
                                              float* __restrict__ Hb) {
  int c = threadIdx.x;
  float s = 0.f;
  for (int b = 0; b < 128; ++b) s += HbP[b * 64 + c];
  Hb[c] = s;
}

// ---------------------------------------------------------------- tiny weight precompute
// wa0 = W@a[:64], wa1 = W@a[64:]; Wn[g][k] = sum_j wihn[g][j]*W[k][j]
__global__ __launch_bounds__(256) void k_wprep(const float* __restrict__ W,
                                               const float* __restrict__ ag,
                                               const float* __restrict__ wihn,
                                               float* __restrict__ wa0,
                                               float* __restrict__ wa1,
                                               float* __restrict__ Wn) {
  __shared__ float sW[64][64];
  __shared__ float sa[128];
  const int t = threadIdx.x;
  for (int l = t; l < 4096; l += 256) sW[l >> 6][l & 63] = W[l];
  if (t < 128) sa[t] = ag[t];
  __syncthreads();
  if (t < 64) {
    float s0 = 0.f, s1 = 0.f;
    for (int j = 0; j < 64; ++j) {
      s0 += sW[t][j] * sa[j];
      s1 += sW[t][j] * sa[64 + j];
    }
    wa0[t] = s0;
    wa1[t] = s1;
  }
  for (int o = t; o < 192 * 64; o += 256) {
    const int g = o >> 6, k = o & 63;
    float s = 0.f;
    for (int j = 0; j < 64; ++j) s += wihn[g * 64 + j] * sW[k][j];
    Wn[o] = s;
  }
}

// ---------------------------------------------------------------- heavy masked matmuls via MFMA
// r2-proven body; KS=16 -> 2048 blocks; launch_bounds(256,4) (no forced spills)
template <int KS>
__global__ __launch_bounds__(256, 4) void k_stageA(
    const float* __restrict__ na, const float* __restrict__ ea,
    const unsigned short* __restrict__ ht,
    float* __restrict__ SpP, float* __restrict__ TfP,
    float* __restrict__ TpP, float* __restrict__ cpP) {
  const int lane  = threadIdx.x & 63;
  const int wid   = threadIdx.x >> 6;
  const int row16 = lane & 15;
  const int kgrp  = lane >> 4;
  const int i0    = blockIdx.x * 64 + wid * 16;
  const int ks    = blockIdx.y;
  const int kbeg  = ks * (NN / KS);

  f32x4 accS[4] = {}, accF[4] = {}, accP[4] = {};
  float cnt = 0.f;

  const float* naRow = na + (size_t)(i0 + row16) * NN;
  const float* eaRow = ea + (size_t)(i0 + row16) * NN;

  for (int k0 = kbeg; k0 < kbeg + NN / KS; k0 += 32) {
    const int kk = k0 + kgrp * 8;
    const float4 a0 = *reinterpret_cast<const float4*>(naRow + kk);
    const float4 a1 = *reinterpret_cast<const float4*>(naRow + kk + 4);
    const float4 e0 = *reinterpret_cast<const float4*>(eaRow + kk);
    const float4 e1 = *reinterpret_cast<const float4*>(eaRow + kk + 4);
    const float av[8] = {a0.x, a0.y, a0.z, a0.w, a1.x, a1.y, a1.z, a1.w};
    const float ev[8] = {e0.x, e0.y, e0.z, e0.w, e1.x, e1.y, e1.z, e1.w};
    bf16x8 fS, fF, fP;
#pragma unroll
    for (int q = 0; q < 8; ++q) {
      fS[q] = (av[q] > 0.f) ? (short)0x3F80 : (short)0;
      fF[q] = f2bf(ev[q]);
      fP[q] = f2bf(fmaxf(ev[q], 0.f));
      cnt += (ev[q] > 0.f) ? 1.f : 0.f;
    }
#pragma unroll
    for (int c = 0; c < 4; ++c) {
      const bf16x8 fB = *reinterpret_cast<const bf16x8*>(
          ht + (size_t)(c * 16 + row16) * NN + kk);
      accS[c] = __builtin_amdgcn_mfma_f32_16x16x32_bf16(fS, fB, accS[c], 0, 0, 0);
      accF[c] = __builtin_amdgcn_mfma_f32_16x16x32_bf16(fF, fB, accF[c], 0, 0, 0);
      accP[c] = __builtin_amdgcn_mfma_f32_16x16x32_bf16(fP, fB, accP[c], 0, 0, 0);
    }
  }
  cnt += __shfl_xor(cnt, 16);
  cnt += __shfl_xor(cnt, 32);
  if (lane < 16) cpP[ks * NN + i0 + lane] = cnt;

  const size_t base = (size_t)ks * ((size_t)NN * HH);
#pragma unroll
  for (int c = 0; c < 4; ++c) {
#pragma unroll
    for (int r = 0; r < 4; ++r) {
      const int row = i0 + kgrp * 4 + r;
      const int col = c * 16 + row16;
      const size_t idx = base + (size_t)row * HH + col;
      SpP[idx] = accS[c][r];
      TfP[idx] = accF[c][r];
      TpP[idx] = accP[c][r];
    }
  }
}

// ---------------------------------------------------------------- combine + analytic GAT (row-parallel)
// Per wave: one row. Produces Sp (->SpP[0]), Sm (->SpP[SZ]), U (->TfP[0]).
template <int KS>
__global__ __launch_bounds__(256) void k_cgat(
    const float* __restrict__ h, const float* __restrict__ dn_g,
    const float* __restrict__ de_g, const float* __restrict__ Hb,
    float* __restrict__ SpP, float* __restrict__ TfP,
    const float* __restrict__ TpP, const float* __restrict__ cpP,
    const float* __restrict__ wa0, const float* __restrict__ wa1) {
  const int lane = threadIdx.x & 63;
  const int wid  = threadIdx.x >> 6;
  const int i    = blockIdx.x * 4 + wid;
  const int idx  = i * 64 + lane;
  const size_t SZ = (size_t)NN * HH;

  float sp = 0.f, tf = 0.f, tp = 0.f;
#pragma unroll
  for (int s = 0; s < KS; ++s) {
    sp += SpP[(size_t)s * SZ + idx];
    tf += TfP[(size_t)s * SZ + idx];
    tp += TpP[(size_t)s * SZ + idx];
  }
  const float hv = h[idx];
  const float dni = dn_g[i], dei = de_g[i];
  sp -= (dni > 0.f) ? hv : 0.f;
  tf -= dei * hv;
  tp -= fmaxf(dei, 0.f) * hv;
  const float sm = Hb[lane] - hv - sp;
  const float tm = tf - tp;

  float cnt = (lane < KS) ? cpP[lane * NN + i] : 0.f;
#pragma unroll
  for (int off = 1; off <= 32; off <<= 1) cnt += __shfl_xor(cnt, off);
  cnt -= (dei > 0.f) ? 1.f : 0.f;

  float ep = sp * wa0[lane] + sm * wa1[lane];
  float em = sm * wa0[lane] + sp * wa1[lane];
#pragma unroll
  for (int off = 32; off >= 1; off >>= 1) {
    ep += __shfl_xor(ep, off);
    em += __shfl_xor(em, off);
  }
  ep = ep > 0.f ? ep : LALPHA * ep;
  em = em > 0.f ? em : LALPHA * em;
  const float cm = (float)(NN - 1) - cnt;
  const float NEGI = -3.0e38f;
  const float m = fmaxf(cnt > 0.f ? ep : NEGI, cm > 0.f ? em : NEGI);
  const float xp = (cnt > 0.f) ? expf(ep - m) : 0.f;
  const float xm = (cm > 0.f) ? expf(em - m) : 0.f;
  const float denom = cnt * xp + cm * xm;
  const float inv = denom > 0.f ? 1.f / denom : 0.f;
  const float wp = xp * inv, wm = xm * inv;

  SpP[idx] = sp;
  SpP[SZ + idx] = sm;
  TfP[idx] = wp * tp + wm * tm;  // U
}

// ---------------------------------------------------------------- GRU-edge (r,z,n), x=[Sp|Sm]
__global__ __launch_bounds__(64) void k_gruE(
    const float* __restrict__ x1, const float* __restrict__ x2,
    const float* __restrict__ wih, const float* __restrict__ whh,
    const float* __restrict__ bih, const float* __restrict__ bhh,
    const float* __restrict__ h, float* __restrict__ out) {
  const int c = threadIdx.x;
  const int i0 = blockIdx.x * 8;
  __shared__ float xs[8][128];
  __shared__ float hs[8][64];
  for (int l = c; l < 8 * 128; l += 64) {
    int r = l >> 7, k = l & 127;
    xs[r][k] = (k < 64) ? x1[(size_t)(i0 + r) * 64 + k]
                        : x2[(size_t)(i0 + r) * 64 + (k - 64)];
  }
  for (int l = c; l < 8 * 64; l += 64) {
    int r = l >> 6, k = l & 63;
    hs[r][k] = h[(size_t)(i0 + r) * 64 + k];
  }
  __syncthreads();
  float gr[8] = {}, gz[8] = {}, gn[8] = {};
  for (int k = 0; k < 128; ++k) {
    float wr = wih[(size_t)c * 128 + k];
    float wz = wih[(size_t)(64 + c) * 128 + k];
    float wn = wih[(size_t)(128 + c) * 128 + k];
#pragma unroll
    for (int r = 0; r < 8; ++r) {
      float xv = xs[r][k];
      gr[r] += xv * wr; gz[r] += xv * wz; gn[r] += xv * wn;
    }
  }
  float hr[8] = {}, hz[8] = {}, hn[8] = {};
  for (int k = 0; k < 64; ++k) {
    float ur = whh[(size_t)c * 64 + k];
    float uz = whh[(size_t)(64 + c) * 64 + k];
    float un = whh[(size_t)(128 + c) * 64 + k];
#pragma unroll
    for (int r = 0; r < 8; ++r) {
      float hv = hs[r][k];
      hr[r] += hv * ur; hz[r] += hv * uz; hn[r] += hv * un;
    }
  }
  float br = bih[c], bz = bih[64 + c], bn = bih[128 + c];
  float dr = bhh[c], dz = bhh[64 + c], dnb = bhh[128 + c];
#pragma unroll
  for (int r = 0; r < 8; ++r) {
    float rg = 1.f / (1.f + expf(-(gr[r] + br + hr[r] + dr)));
    float zg = 1.f / (1.f + expf(-(gz[r] + bz + hz[r] + dz)));
    float ng = tanhf(gn[r] + bn + rg * (hn[r] + dnb));
    out[(size_t)(i0 + r) * 64 + c] = (1.f - zg) * ng + zg * hs[r][c];
  }
}

// ---------------------------------------------------------------- GRU-node (x = U via Wn) + final combine
__global__ __launch_bounds__(64) void k_gruNF(
    const float* __restrict__ U, const float* __restrict__ Wn,
    const float* __restrict__ whh, const float* __restrict__ bih,
    const float* __restrict__ bhh, const float* __restrict__ h,
    const float* __restrict__ EO, const float* __restrict__ dn_g,
    const float* __restrict__ de_g, float* __restrict__ out) {
  const int c = threadIdx.x;
  const int i0 = blockIdx.x * 8;
  __shared__ float xs[8][64];
  __shared__ float hs[8][64];
  for (int l = c; l < 8 * 64; l += 64) {
    int r = l >> 6, k = l & 63;
    xs[r][k] = U[(size_t)(i0 + r) * 64 + k];
    hs[r][k] = h[(size_t)(i0 + r) * 64 + k];
  }
  __syncthreads();
  float gr[8] = {}, gz[8] = {}, gn[8] = {};
  for (int k = 0; k < 64; ++k) {
    float wr = Wn[(size_t)c * 64 + k];
    float wz = Wn[(size_t)(64 + c) * 64 + k];
    float wn = Wn[(size_t)(128 + c) * 64 + k];
#pragma unroll
    for (int r = 0; r < 8; ++r) {
      float xv = xs[r][k];
      gr[r] += xv * wr; gz[r] += xv * wz; gn[r] += xv * wn;
    }
  }
  float hr[8] = {}, hz[8] = {}, hn[8] = {};
  for (int k = 0; k < 64; ++k) {
    float ur = whh[(size_t)c * 64 + k];
    float uz = whh[(size_t)(64 + c) * 64 + k];
    float un = whh[(size_t)(128 + c) * 64 + k];
#pragma unroll
    for (int r = 0; r < 8; ++r) {
      float hv = hs[r][k];
      hr[r] += hv * ur; hz[r] += hv * uz; hn[r] += hv * un;
    }
  }
  float br = bih[c], bz = bih[64 + c], bn = bih[128 + c];
  float dr = bhh[c], dz = bhh[64 + c], dnb = bhh[128 + c];
#pragma unroll
  for (int r = 0; r < 8; ++r) {
    float rg = 1.f / (1.f + expf(-(gr[r] + br + hr[r] + dr)));
    float zg = 1.f / (1.f + expf(-(gz[r] + bz + hz[r] + dz)));
    float ng = tanhf(gn[r] + bn + rg * (hn[r] + dnb));
    float no = (1.f - zg) * ng + zg * hs[r][c];
    const int row = i0 + r;
    out[(size_t)row * 64 + c] =
        de_g[row] * EO[(size_t)row * 64 + c] + dn_g[row] * no;
  }
}

// ---------------------------------------------------------------- launch
template <int KS>
static void launch_all(const float* h, const float* na, const float* ea,
                       const float* Wg, const float* ag, const float* wihe,
                       const float* whhe, const float* bihe, const float* bhhe,
                       const float* wihn, const float* whhn, const float* bihn,
                       const float* bhhn, float* out, float* ws,
                       hipStream_t stream) {
  const size_t SZ = (size_t)NN * HH;
  float* SpP = ws;                              // KS*SZ ; finals Sp=+0, Sm=+SZ
  float* TfP = ws + (size_t)KS * SZ;            // KS*SZ ; final U=+0
  float* TpP = ws + (size_t)2 * KS * SZ;        // KS*SZ ; EO=+0 (after cgat)
  float* cpP = ws + (size_t)3 * KS * SZ;        // KS*NN
  float* dn  = cpP + (size_t)KS * NN;           // NN
  float* de  = dn + NN;                         // NN
  float* HbP = de + NN;                         // 128*64
  float* Hb  = HbP + 128 * 64;                  // 64
  float* wa0 = Hb + 64;                         // 64
  float* wa1 = wa0 + 64;                        // 64
  float* Wn  = wa1 + 64;                        // 192*64
  unsigned short* ht = (unsigned short*)(Wn + 192 * 64);
  float* Sp = SpP;
  float* Sm = SpP + SZ;
  float* U  = TfP;
  float* EO = TpP;

  k_prep<<<NN / 64, 256, 0, stream>>>(h, na, ea, ht, dn, de, HbP);
  k_hbarF<<<1, 64, 0, stream>>>(HbP, Hb);
  k_wprep<<<1, 256, 0, stream>>>(Wg, ag, wihn, wa0, wa1, Wn);
  k_stageA<KS><<<dim3(NN / 64, KS), 256, 0, stream>>>(na, ea, ht, SpP, TfP, TpP, cpP);
  k_cgat<KS><<<NN / 4, 256, 0, stream>>>(h, dn, de, Hb, SpP, TfP, TpP, cpP, wa0, wa1);
  k_gruE<<<NN / 8, 64, 0, stream>>>(Sp, Sm, wihe, whhe, bihe, bhhe, h, EO);
  k_gruNF<<<NN / 8, 64, 0, stream>>>(U, Wn, whhn, bihn, bhhn, h, EO, dn, de, out);
}

extern "C" void kernel_launch(void* const* d_in, const int* in_sizes, int n_in,
                              void* d_out, int out_size, void* d_ws, size_t ws_size,
                              hipStream_t stream) {
  const float* h    = (const float*)d_in[0];
  const float* na   = (const float*)d_in[1];
  const float* ea   = (const float*)d_in[2];
  const float* Wg   = (const float*)d_in[3];
  const float* ag   = (const float*)d_in[4];
  const float* wihe = (const float*)d_in[5];
  const float* whhe = (const float*)d_in[6];
  const float* bihe = (const float*)d_in[7];
  const float* bhhe = (const float*)d_in[8];
  const float* wihn = (const float*)d_in[9];
  const float* whhn = (const float*)d_in[10];
  const float* bihn = (const float*)d_in[11];
  const float* bhhn = (const float*)d_in[12];
  float* out = (float*)d_out;
  float* ws  = (float*)d_ws;

  const size_t SZ = (size_t)NN * HH;
  auto need = [&](int ks) {
    return (3 * (size_t)ks * SZ + (size_t)ks * NN + 2 * NN + 128 * 64 + 64 +
            128 + 192 * 64) * 4 + (size_t)NN * HH * 2;
  };
  if (ws_size >= need(16)) {
    launch_all<16>(h, na, ea, Wg, ag, wihe, whhe, bihe, bhhe, wihn, whhn,
                   bihn, bhhn, out, ws, stream);
  } else if (ws_size >= need(8)) {
    launch_all<8>(h, na, ea, Wg, ag, wihe, whhe, bihe, bhhe, wihn, whhn,
                  bihn, bhhn, out, ws, stream);
  } else {
    launch_all<4>(h, na, ea, Wg, ag, wihe, whhe, bihe, bhhe, wihn, whhn,
                  bihn, bhhn, out, ws, stream);
  }
}

// Round 8
// 305.523 us; speedup vs baseline: 4.5555x; 1.0218x over previous
//
#include <hip/hip_runtime.h>

#define NN 8192
#define HH 64
constexpr float LALPHA = 0.2f;

typedef __attribute__((ext_vector_type(8))) short bf16x8;
typedef __attribute__((ext_vector_type(4))) float f32x4;

__device__ inline short f2bf(float f) {
  unsigned u = __builtin_bit_cast(unsigned, f);
  u += 0x7FFFu + ((u >> 16) & 1u);
  return (short)(u >> 16);
}

// ---------------------------------------------------------------- prep: ht transpose + diag + column-sum partials
__global__ __launch_bounds__(256) void k_prep(const float* __restrict__ h,
                                              const float* __restrict__ na,
                                              const float* __restrict__ ea,
                                              unsigned short* __restrict__ ht,
                                              float* __restrict__ dn,
                                              float* __restrict__ de,
                                              float* __restrict__ HbP) {
  __shared__ float tile[64][65];
  const int j0 = blockIdx.x * 64;
  for (int l = threadIdx.x; l < 64 * 64; l += 256) {
    int r = l >> 6, c = l & 63;
    tile[r][c] = h[(size_t)(j0 + r) * HH + c];
  }
  __syncthreads();
  for (int l = threadIdx.x; l < 64 * 64; l += 256) {
    int c = l >> 6, r = l & 63;
    ht[(size_t)c * NN + j0 + r] = (unsigned short)f2bf(tile[r][c]);
  }
  const int t = threadIdx.x;
  if (t < 64) {
    float s = 0.f;
    for (int r = 0; r < 64; ++r) s += tile[r][t];
    HbP[blockIdx.x * 64 + t] = s;
  } else if (t < 128) {
    int i = j0 + (t - 64);
    dn[i] = na[(size_t)i * NN + i];
    de[i] = ea[(size_t)i * NN + i];
  }
}

__global__ __launch_bounds__(64) void k_hbarF(const float* __restrict__ HbP,
                                              float* __restrict__ Hb) {
  int c = threadIdx.x;
  float s = 0.f;
  for (int b = 0; b < 128; ++b) s += HbP[b * 64 + c];
  Hb[c] = s;
}

// ---------------------------------------------------------------- tiny weight precompute
__global__ __launch_bounds__(256) void k_wprep(const float* __restrict__ W,
                                               const float* __restrict__ ag,
                                               const float* __restrict__ wihn,
                                               float* __restrict__ wa0,
                                               float* __restrict__ wa1,
                                               float* __restrict__ Wn) {
  __shared__ float sW[64][64];
  __shared__ float sa[128];
  const int t = threadIdx.x;
  for (int l = t; l < 4096; l += 256) sW[l >> 6][l & 63] = W[l];
  if (t < 128) sa[t] = ag[t];
  __syncthreads();
  if (t < 64) {
    float s0 = 0.f, s1 = 0.f;
    for (int j = 0; j < 64; ++j) {
      s0 += sW[t][j] * sa[j];
      s1 += sW[t][j] * sa[64 + j];
    }
    wa0[t] = s0;
    wa1[t] = s1;
  }
  for (int o = t; o < 192 * 64; o += 256) {
    const int g = o >> 6, k = o & 63;
    float s = 0.f;
    for (int j = 0; j < 64; ++j) s += wihn[g * 64 + j] * sW[k][j];
    Wn[o] = s;
  }
}

// ---------------------------------------------------------------- heavy masked matmuls via MFMA
// D=4 rotating register pipeline on the HBM adjacency streams; statically
// indexed sets inside an unroll-4 body; loads for t+4 issue before t's MFMAs.
template <int KS>
__global__ __launch_bounds__(256) void k_stageA(
    const float* __restrict__ na, const float* __restrict__ ea,
    const unsigned short* __restrict__ ht,
    float* __restrict__ SpP, float* __restrict__ TfP,
    float* __restrict__ TpP, float* __restrict__ cpP) {
  const int lane  = threadIdx.x & 63;
  const int wid   = threadIdx.x >> 6;
  const int row16 = lane & 15;
  const int kgrp  = lane >> 4;
  const int i0    = blockIdx.x * 64 + wid * 16;
  const int ks    = blockIdx.y;
  const int kbeg  = ks * (NN / KS);
  constexpr int ITERS = NN / KS / 32;  // divisible by 4 for KS in {4,8}

  f32x4 accS[4] = {}, accF[4] = {}, accP[4] = {};
  float cnt = 0.f;

  const float* naRow = na + (size_t)(i0 + row16) * NN + kbeg + kgrp * 8;
  const float* eaRow = ea + (size_t)(i0 + row16) * NN + kbeg + kgrp * 8;
  const unsigned short* htRow = ht + (size_t)row16 * NN + kbeg + kgrp * 8;

  f32x4 A0[4], A1[4], E0[4], E1[4];

#define LOADA(d, koff)                                        \
  do {                                                        \
    A0[d] = *reinterpret_cast<const f32x4*>(naRow + (koff));  \
    A1[d] = *reinterpret_cast<const f32x4*>(naRow + (koff) + 4); \
    E0[d] = *reinterpret_cast<const f32x4*>(eaRow + (koff));  \
    E1[d] = *reinterpret_cast<const f32x4*>(eaRow + (koff) + 4); \
  } while (0)

#pragma unroll
  for (int d = 0; d < 4; ++d) LOADA(d, d * 32);

  for (int t = 0; t < ITERS; t += 4) {
#pragma unroll
    for (int d = 0; d < 4; ++d) {
      const int tc = t + d;
      const int kk = tc * 32;
      // ht B-fragments (L2-resident) for current iter
      const bf16x8 B0 = *reinterpret_cast<const bf16x8*>(htRow + kk);
      const bf16x8 B1 = *reinterpret_cast<const bf16x8*>(htRow + (size_t)16 * NN + kk);
      const bf16x8 B2 = *reinterpret_cast<const bf16x8*>(htRow + (size_t)32 * NN + kk);
      const bf16x8 B3 = *reinterpret_cast<const bf16x8*>(htRow + (size_t)48 * NN + kk);
      // consume current adjacency set into converts
      const float av[8] = {A0[d][0], A0[d][1], A0[d][2], A0[d][3],
                           A1[d][0], A1[d][1], A1[d][2], A1[d][3]};
      const float ev[8] = {E0[d][0], E0[d][1], E0[d][2], E0[d][3],
                           E1[d][0], E1[d][1], E1[d][2], E1[d][3]};
      bf16x8 fS, fF, fP;
#pragma unroll
      for (int q = 0; q < 8; ++q) {
        fS[q] = (av[q] > 0.f) ? (short)0x3F80 : (short)0;
        fF[q] = f2bf(ev[q]);
        fP[q] = f2bf(fmaxf(ev[q], 0.f));
        cnt += (ev[q] > 0.f) ? 1.f : 0.f;
      }
      // refill slot d with iter tc+4 (clamped: harmless redundant L2 hit at tail)
      const int tn = tc + 4;
      LOADA(d, (tn < ITERS ? tn : tc) * 32);
      // MFMAs for current iter
      accS[0] = __builtin_amdgcn_mfma_f32_16x16x32_bf16(fS, B0, accS[0], 0, 0, 0);
      accF[0] = __builtin_amdgcn_mfma_f32_16x16x32_bf16(fF, B0, accF[0], 0, 0, 0);
      accP[0] = __builtin_amdgcn_mfma_f32_16x16x32_bf16(fP, B0, accP[0], 0, 0, 0);
      accS[1] = __builtin_amdgcn_mfma_f32_16x16x32_bf16(fS, B1, accS[1], 0, 0, 0);
      accF[1] = __builtin_amdgcn_mfma_f32_16x16x32_bf16(fF, B1, accF[1], 0, 0, 0);
      accP[1] = __builtin_amdgcn_mfma_f32_16x16x32_bf16(fP, B1, accP[1], 0, 0, 0);
      accS[2] = __builtin_amdgcn_mfma_f32_16x16x32_bf16(fS, B2, accS[2], 0, 0, 0);
      accF[2] = __builtin_amdgcn_mfma_f32_16x16x32_bf16(fF, B2, accF[2], 0, 0, 0);
      accP[2] = __builtin_amdgcn_mfma_f32_16x16x32_bf16(fP, B2, accP[2], 0, 0, 0);
      accS[3] = __builtin_amdgcn_mfma_f32_16x16x32_bf16(fS, B3, accS[3], 0, 0, 0);
      accF[3] = __builtin_amdgcn_mfma_f32_16x16x32_bf16(fF, B3, accF[3], 0, 0, 0);
      accP[3] = __builtin_amdgcn_mfma_f32_16x16x32_bf16(fP, B3, accP[3], 0, 0, 0);
    }
  }
#undef LOADA

  cnt += __shfl_xor(cnt, 16);
  cnt += __shfl_xor(cnt, 32);
  if (lane < 16) cpP[ks * NN + i0 + lane] = cnt;

  const size_t base = (size_t)ks * ((size_t)NN * HH);
#pragma unroll
  for (int c = 0; c < 4; ++c) {
#pragma unroll
    for (int r = 0; r < 4; ++r) {
      const int row = i0 + kgrp * 4 + r;
      const int col = c * 16 + row16;
      const size_t idx = base + (size_t)row * HH + col;
      SpP[idx] = accS[c][r];
      TfP[idx] = accF[c][r];
      TpP[idx] = accP[c][r];
    }
  }
}

// ---------------------------------------------------------------- combine + analytic GAT (row-parallel)
template <int KS>
__global__ __launch_bounds__(256) void k_cgat(
    const float* __restrict__ h, const float* __restrict__ dn_g,
    const float* __restrict__ de_g, const float* __restrict__ Hb,
    float* __restrict__ SpP, float* __restrict__ TfP,
    const float* __restrict__ TpP, const float* __restrict__ cpP,
    const float* __restrict__ wa0, const float* __restrict__ wa1) {
  const int lane = threadIdx.x & 63;
  const int wid  = threadIdx.x >> 6;
  const int i    = blockIdx.x * 4 + wid;
  const int idx  = i * 64 + lane;
  const size_t SZ = (size_t)NN * HH;

  float sp = 0.f, tf = 0.f, tp = 0.f;
#pragma unroll
  for (int s = 0; s < KS; ++s) {
    sp += SpP[(size_t)s * SZ + idx];
    tf += TfP[(size_t)s * SZ + idx];
    tp += TpP[(size_t)s * SZ + idx];
  }
  const float hv = h[idx];
  const float dni = dn_g[i], dei = de_g[i];
  sp -= (dni > 0.f) ? hv : 0.f;
  tf -= dei * hv;
  tp -= fmaxf(dei, 0.f) * hv;
  const float sm = Hb[lane] - hv - sp;
  const float tm = tf - tp;

  float cnt = (lane < KS) ? cpP[lane * NN + i] : 0.f;
#pragma unroll
  for (int off = 1; off <= 32; off <<= 1) cnt += __shfl_xor(cnt, off);
  cnt -= (dei > 0.f) ? 1.f : 0.f;

  float ep = sp * wa0[lane] + sm * wa1[lane];
  float em = sm * wa0[lane] + sp * wa1[lane];
#pragma unroll
  for (int off = 32; off >= 1; off >>= 1) {
    ep += __shfl_xor(ep, off);
    em += __shfl_xor(em, off);
  }
  ep = ep > 0.f ? ep : LALPHA * ep;
  em = em > 0.f ? em : LALPHA * em;
  const float cm = (float)(NN - 1) - cnt;
  const float NEGI = -3.0e38f;
  const float m = fmaxf(cnt > 0.f ? ep : NEGI, cm > 0.f ? em : NEGI);
  const float xp = (cnt > 0.f) ? expf(ep - m) : 0.f;
  const float xm = (cm > 0.f) ? expf(em - m) : 0.f;
  const float denom = cnt * xp + cm * xm;
  const float inv = denom > 0.f ? 1.f / denom : 0.f;
  const float wp = xp * inv, wm = xm * inv;

  SpP[idx] = sp;
  SpP[SZ + idx] = sm;
  TfP[idx] = wp * tp + wm * tm;  // U
}

// ---------------------------------------------------------------- GRU-edge (r,z,n), x=[Sp|Sm], 32 rows/block
__global__ __launch_bounds__(256) void k_gruE(
    const float* __restrict__ x1, const float* __restrict__ x2,
    const float* __restrict__ wih, const float* __restrict__ whh,
    const float* __restrict__ bih, const float* __restrict__ bhh,
    const float* __restrict__ h, float* __restrict__ out) {
  const int c  = threadIdx.x & 63;
  const int rg = threadIdx.x >> 6;
  const int i0 = blockIdx.x * 32 + rg * 8;
  __shared__ float xs[32][128];
  __shared__ float hs[32][64];
  for (int l = c; l < 8 * 128; l += 64) {
    int r = l >> 7, k = l & 127;
    xs[rg * 8 + r][k] = (k < 64) ? x1[(size_t)(i0 + r) * 64 + k]
                                 : x2[(size_t)(i0 + r) * 64 + (k - 64)];
  }
  for (int l = c; l < 8 * 64; l += 64) {
    int r = l >> 6, k = l & 63;
    hs[rg * 8 + r][k] = h[(size_t)(i0 + r) * 64 + k];
  }
  __syncthreads();
  float gr[8] = {}, gz[8] = {}, gn[8] = {};
  for (int k = 0; k < 128; ++k) {
    float wr = wih[(size_t)c * 128 + k];
    float wz = wih[(size_t)(64 + c) * 128 + k];
    float wn = wih[(size_t)(128 + c) * 128 + k];
#pragma unroll
    for (int r = 0; r < 8; ++r) {
      float xv = xs[rg * 8 + r][k];
      gr[r] += xv * wr; gz[r] += xv * wz; gn[r] += xv * wn;
    }
  }
  float hr[8] = {}, hz[8] = {}, hn[8] = {};
  for (int k = 0; k < 64; ++k) {
    float ur = whh[(size_t)c * 64 + k];
    float uz = whh[(size_t)(64 + c) * 64 + k];
    float un = whh[(size_t)(128 + c) * 64 + k];
#pragma unroll
    for (int r = 0; r < 8; ++r) {
      float hv = hs[rg * 8 + r][k];
      hr[r] += hv * ur; hz[r] += hv * uz; hn[r] += hv * un;
    }
  }
  float br = bih[c], bz = bih[64 + c], bn = bih[128 + c];
  float dr = bhh[c], dz = bhh[64 + c], dnb = bhh[128 + c];
#pragma unroll
  for (int r = 0; r < 8; ++r) {
    float rg_ = 1.f / (1.f + expf(-(gr[r] + br + hr[r] + dr)));
    float zg = 1.f / (1.f + expf(-(gz[r] + bz + hz[r] + dz)));
    float ng = tanhf(gn[r] + bn + rg_ * (hn[r] + dnb));
    out[(size_t)(i0 + r) * 64 + c] = (1.f - zg) * ng + zg * hs[rg * 8 + r][c];
  }
}

// ---------------------------------------------------------------- GRU-node (x = U via Wn) + final, 32 rows/block
__global__ __launch_bounds__(256) void k_gruNF(
    const float* __restrict__ U, const float* __restrict__ Wn,
    const float* __restrict__ whh, const float* __restrict__ bih,
    const float* __restrict__ bhh, const float* __restrict__ h,
    const float* __restrict__ EO, const float* __restrict__ dn_g,
    const float* __restrict__ de_g, float* __restrict__ out) {
  const int c  = threadIdx.x & 63;
  const int rg = threadIdx.x >> 6;
  const int i0 = blockIdx.x * 32 + rg * 8;
  __shared__ float xs[32][64];
  __shared__ float hs[32][64];
  for (int l = c; l < 8 * 64; l += 64) {
    int r = l >> 6, k = l & 63;
    xs[rg * 8 + r][k] = U[(size_t)(i0 + r) * 64 + k];
    hs[rg * 8 + r][k] = h[(size_t)(i0 + r) * 64 + k];
  }
  __syncthreads();
  float gr[8] = {}, gz[8] = {}, gn[8] = {};
  for (int k = 0; k < 64; ++k) {
    float wr = Wn[(size_t)c * 64 + k];
    float wz = Wn[(size_t)(64 + c) * 64 + k];
    float wn = Wn[(size_t)(128 + c) * 64 + k];
#pragma unroll
    for (int r = 0; r < 8; ++r) {
      float xv = xs[rg * 8 + r][k];
      gr[r] += xv * wr; gz[r] += xv * wz; gn[r] += xv * wn;
    }
  }
  float hr[8] = {}, hz[8] = {}, hn[8] = {};
  for (int k = 0; k < 64; ++k) {
    float ur = whh[(size_t)c * 64 + k];
    float uz = whh[(size_t)(64 + c) * 64 + k];
    float un = whh[(size_t)(128 + c) * 64 + k];
#pragma unroll
    for (int r = 0; r < 8; ++r) {
      float hv = hs[rg * 8 + r][k];
      hr[r] += hv * ur; hz[r] += hv * uz; hn[r] += hv * un;
    }
  }
  float br = bih[c], bz = bih[64 + c], bn = bih[128 + c];
  float dr = bhh[c], dz = bhh[64 + c], dnb = bhh[128 + c];
#pragma unroll
  for (int r = 0; r < 8; ++r) {
    float rg_ = 1.f / (1.f + expf(-(gr[r] + br + hr[r] + dr)));
    float zg = 1.f / (1.f + expf(-(gz[r] + bz + hz[r] + dz)));
    float ng = tanhf(gn[r] + bn + rg_ * (hn[r] + dnb));
    float no = (1.f - zg) * ng + zg * hs[rg * 8 + r][c];
    const int row = i0 + r;
    out[(size_t)row * 64 + c] =
        de_g[row] * EO[(size_t)row * 64 + c] + dn_g[row] * no;
  }
}

// ---------------------------------------------------------------- launch
template <int KS>
static void launch_all(const float* h, const float* na, const float* ea,
                       const float* Wg, const float* ag, const float* wihe,
                       const float* whhe, const float* bihe, const float* bhhe,
                       const float* wihn, const float* whhn, const float* bihn,
                       const float* bhhn, float* out, float* ws,
                       hipStream_t stream) {
  const size_t SZ = (size_t)NN * HH;
  float* SpP = ws;                              // KS*SZ ; finals Sp=+0, Sm=+SZ
  float* TfP = ws + (size_t)KS * SZ;            // KS*SZ ; final U=+0
  float* TpP = ws + (size_t)2 * KS * SZ;        // KS*SZ ; EO=+0 (after cgat)
  float* cpP = ws + (size_t)3 * KS * SZ;        // KS*NN
  float* dn  = cpP + (size_t)KS * NN;           // NN
  float* de  = dn + NN;                         // NN
  float* HbP = de + NN;                         // 128*64
  float* Hb  = HbP + 128 * 64;                  // 64
  float* wa0 = Hb + 64;                         // 64
  float* wa1 = wa0 + 64;                        // 64
  float* Wn  = wa1 + 64;                        // 192*64
  unsigned short* ht = (unsigned short*)(Wn + 192 * 64);
  float* Sp = SpP;
  float* Sm = SpP + SZ;
  float* U  = TfP;
  float* EO = TpP;

  k_prep<<<NN / 64, 256, 0, stream>>>(h, na, ea, ht, dn, de, HbP);
  k_hbarF<<<1, 64, 0, stream>>>(HbP, Hb);
  k_wprep<<<1, 256, 0, stream>>>(Wg, ag, wihn, wa0, wa1, Wn);
  k_stageA<KS><<<dim3(NN / 64, KS), 256, 0, stream>>>(na, ea, ht, SpP, TfP, TpP, cpP);
  k_cgat<KS><<<NN / 4, 256, 0, stream>>>(h, dn, de, Hb, SpP, TfP, TpP, cpP, wa0, wa1);
  k_gruE<<<NN / 32, 256, 0, stream>>>(Sp, Sm, wihe, whhe, bihe, bhhe, h, EO);
  k_gruNF<<<NN / 32, 256, 0, stream>>>(U, Wn, whhn, bihn, bhhn, h, EO, dn, de, out);
}

extern "C" void kernel_launch(void* const* d_in, const int* in_sizes, int n_in,
                              void* d_out, int out_size, void* d_ws, size_t ws_size,
                              hipStream_t stream) {
  const float* h    = (const float*)d_in[0];
  const float* na   = (const float*)d_in[1];
  const float* ea   = (const float*)d_in[2];
  const float* Wg   = (const float*)d_in[3];
  const float* ag   = (const float*)d_in[4];
  const float* wihe = (const float*)d_in[5];
  const float* whhe = (const float*)d_in[6];
  const float* bihe = (const float*)d_in[7];
  const float* bhhe = (const float*)d_in[8];
  const float* wihn = (const float*)d_in[9];
  const float* whhn = (const float*)d_in[10];
  const float* bihn = (const float*)d_in[11];
  const float* bhhn = (const float*)d_in[12];
  float* out = (float*)d_out;
  float* ws  = (float*)d_ws;

  const size_t SZ = (size_t)NN * HH;
  auto need = [&](int ks) {
    return (3 * (size_t)ks * SZ + (size_t)ks * NN + 2 * NN + 128 * 64 + 64 +
            128 + 192 * 64) * 4 + (size_t)NN * HH * 2;
  };
  if (ws_size >= need(8)) {
    launch_all<8>(h, na, ea, Wg, ag, wihe, whhe, bihe, bhhe, wihn, whhn,
                  bihn, bhhn, out, ws, stream);
  } else {
    launch_all<4>(h, na, ea, Wg, ag, wihe, whhe, bihe, bhhe, wihn, whhn,
                  bihn, bhhn, out, ws, stream);
  }
}

// Round 9
// 274.950 us; speedup vs baseline: 5.0621x; 1.1112x over previous
//
#include <hip/hip_runtime.h>

#define NN 8192
#define HH 64
#define BK 128
constexpr float LALPHA = 0.2f;

typedef __attribute__((ext_vector_type(8))) short bf16x8;
typedef __attribute__((ext_vector_type(4))) short s16x4;
typedef __attribute__((ext_vector_type(4))) float f32x4;

__device__ inline short f2bf(float f) {
  unsigned u = __builtin_bit_cast(unsigned, f);
  u += 0x7FFFu + ((u >> 16) & 1u);
  return (short)(u >> 16);
}

// ---------------------------------------------------------------- prep: ht transpose + diag + column-sum partials
__global__ __launch_bounds__(256) void k_prep(const float* __restrict__ h,
                                              const float* __restrict__ na,
                                              const float* __restrict__ ea,
                                              unsigned short* __restrict__ ht,
                                              float* __restrict__ dn,
                                              float* __restrict__ de,
                                              float* __restrict__ HbP) {
  __shared__ float tile[64][65];
  const int j0 = blockIdx.x * 64;
  for (int l = threadIdx.x; l < 64 * 64; l += 256) {
    int r = l >> 6, c = l & 63;
    tile[r][c] = h[(size_t)(j0 + r) * HH + c];
  }
  __syncthreads();
  for (int l = threadIdx.x; l < 64 * 64; l += 256) {
    int c = l >> 6, r = l & 63;
    ht[(size_t)c * NN + j0 + r] = (unsigned short)f2bf(tile[r][c]);
  }
  const int t = threadIdx.x;
  if (t < 64) {
    float s = 0.f;
    for (int r = 0; r < 64; ++r) s += tile[r][t];
    HbP[blockIdx.x * 64 + t] = s;
  } else if (t < 128) {
    int i = j0 + (t - 64);
    dn[i] = na[(size_t)i * NN + i];
    de[i] = ea[(size_t)i * NN + i];
  }
}

// ---------------------------------------------------------------- weight prep: transposes, Wn fold, wa, Hb
__global__ __launch_bounds__(256) void k_wprep(
    const float* __restrict__ W, const float* __restrict__ ag,
    const float* __restrict__ wihe, const float* __restrict__ whhe,
    const float* __restrict__ wihn, const float* __restrict__ whhn,
    const float* __restrict__ HbP, float* __restrict__ Hb,
    float* __restrict__ wa0, float* __restrict__ wa1,
    float* __restrict__ wihTe, float* __restrict__ whhTe,
    float* __restrict__ WnT, float* __restrict__ whhTn) {
  const int bid = blockIdx.x, t = threadIdx.x;
  if (bid == 64) {
    __shared__ float sW[64][64];
    __shared__ float sa[128];
    for (int l = t; l < 4096; l += 256) sW[l >> 6][l & 63] = W[l];
    if (t < 128) sa[t] = ag[t];
    __syncthreads();
    if (t < 64) {
      float s0 = 0.f, s1 = 0.f;
      for (int j = 0; j < 64; ++j) {
        s0 += sW[t][j] * sa[j];
        s1 += sW[t][j] * sa[64 + j];
      }
      wa0[t] = s0;
      wa1[t] = s1;
    } else if (t < 128) {
      int c = t - 64;
      float s = 0.f;
      for (int b = 0; b < 128; ++b) s += HbP[b * 64 + c];
      Hb[c] = s;
    }
    return;
  }
  // plain transposes (flat)
  for (int x = bid * 256 + t; x < 49152; x += 64 * 256) {
    if (x < 24576) {
      int k = x / 192, g = x % 192;
      wihTe[x] = wihe[g * 128 + k];
    } else if (x < 36864) {
      int o = x - 24576, k = o / 192, g = o % 192;
      whhTe[o] = whhe[g * 64 + k];
    } else {
      int o = x - 36864, k = o / 192, g = o % 192;
      whhTn[o] = whhn[g * 64 + k];
    }
  }
  // WnT[k*192+g] = sum_j wihn[g][j] * W[k][j]
  if (bid < 48) {
    const int o = bid * 256 + t;
    const int k = o / 192, g = o % 192;
    float s = 0.f;
    for (int j = 0; j < 64; ++j) s += wihn[g * 64 + j] * W[k * 64 + j];
    WnT[o] = s;
  }
}

// ---------------------------------------------------------------- staged streaming MFMA kernels
// Global reads: 512B-contiguous runs per row (lane-major), reg-staged, bf16
// converted, XOR-swizzled ds_write; fragments via conflict-free ds_read_b128.
// 2-step-deep prefetch: GA/GB reg sets + LDS double buffer.
template <int KSP>
__global__ __launch_bounds__(256) void k_stageEA(
    const float* __restrict__ ea, const unsigned short* __restrict__ ht,
    float* __restrict__ TfP, float* __restrict__ TpP, float* __restrict__ cpP) {
  constexpr int NSTEP = (NN / KSP) / BK;  // 16 (KSP=4), 32 (KSP=2): even
  __shared__ __align__(16) short lsF[2][64 * BK];
  const int t = threadIdx.x;
  const int lane = t & 63, w = t >> 6;
  const int row16 = lane & 15, kgrp = lane >> 4;
  const int i0t = blockIdx.x * 64;
  const int kbeg = blockIdx.y * (NN / KSP);

  const float* gsrc[8];
  int sidx[8];
#pragma unroll
  for (int j = 0; j < 8; ++j) {
    const int v = t + 256 * j;
    const int row = v >> 5, col8 = v & 31;
    gsrc[j] = ea + (size_t)(i0t + row) * NN + kbeg + col8 * 4;
    sidx[j] = row * BK + (((col8 >> 1) ^ (row & 15)) * 8) + (col8 & 1) * 4;
  }

  f32x4 GA[8], GB[8];
  f32x4 accF[4] = {}, accP[4] = {};
  float cnt = 0.f;

#define ISSUE(G, step)                                                       \
  { _Pragma("unroll") for (int j = 0; j < 8; ++j)                            \
        G[j] = *reinterpret_cast<const f32x4*>(gsrc[j] + (step) * BK); }

#define WRITE(b, G)                                                          \
  { _Pragma("unroll") for (int j = 0; j < 8; ++j) {                          \
      s16x4 o;                                                               \
      _Pragma("unroll") for (int q = 0; q < 4; ++q) o[q] = f2bf(G[j][q]);    \
      *reinterpret_cast<s16x4*>(&lsF[b][sidx[j]]) = o;                       \
    } }

#define CONSUME(b, stp)                                                      \
  { _Pragma("unroll") for (int s = 0; s < 4; ++s) {                          \
      const int R = w * 16 + row16;                                          \
      const int slot = (s * 4 + kgrp) ^ row16;                               \
      const bf16x8 fF =                                                      \
          *reinterpret_cast<const bf16x8*>(&lsF[b][R * BK + slot * 8]);      \
      bf16x8 fP;                                                             \
      _Pragma("unroll") for (int q = 0; q < 8; ++q) {                        \
        const short sv = fF[q];                                              \
        fP[q] = sv > 0 ? sv : (short)0;                                      \
        cnt += sv > 0 ? 1.f : 0.f;                                           \
      }                                                                      \
      const size_t kg = (size_t)kbeg + (size_t)(stp)*BK + s * 32 + kgrp * 8; \
      _Pragma("unroll") for (int c = 0; c < 4; ++c) {                        \
        const bf16x8 B = *reinterpret_cast<const bf16x8*>(                   \
            ht + (size_t)(c * 16 + row16) * NN + kg);                        \
        accF[c] = __builtin_amdgcn_mfma_f32_16x16x32_bf16(fF, B, accF[c], 0, 0, 0); \
        accP[c] = __builtin_amdgcn_mfma_f32_16x16x32_bf16(fP, B, accP[c], 0, 0, 0); \
      }                                                                      \
    } }

  ISSUE(GA, 0);
  ISSUE(GB, 1);
  WRITE(0, GA);
  ISSUE(GA, 2);
  __syncthreads();
  for (int ss = 0; ss < NSTEP; ss += 2) {
    CONSUME(0, ss);
    __syncthreads();
    WRITE(1, GB);
    if (ss + 3 < NSTEP) ISSUE(GB, ss + 3);
    __syncthreads();
    CONSUME(1, ss + 1);
    __syncthreads();
    if (ss + 2 < NSTEP) {
      WRITE(0, GA);
      if (ss + 4 < NSTEP) ISSUE(GA, ss + 4);
    }
    __syncthreads();
  }
#undef ISSUE
#undef WRITE
#undef CONSUME

  cnt += __shfl_xor(cnt, 16);
  cnt += __shfl_xor(cnt, 32);
  if (lane < 16) cpP[blockIdx.y * NN + i0t + w * 16 + lane] = cnt;

  const size_t base = (size_t)blockIdx.y * ((size_t)NN * HH);
#pragma unroll
  for (int c = 0; c < 4; ++c) {
#pragma unroll
    for (int r = 0; r < 4; ++r) {
      const int row = i0t + w * 16 + kgrp * 4 + r;
      const int col = c * 16 + row16;
      const size_t idx = base + (size_t)row * HH + col;
      TfP[idx] = accF[c][r];
      TpP[idx] = accP[c][r];
    }
  }
}

template <int KSP>
__global__ __launch_bounds__(256) void k_stageNA(
    const float* __restrict__ na, const unsigned short* __restrict__ ht,
    float* __restrict__ SpP) {
  constexpr int NSTEP = (NN / KSP) / BK;
  __shared__ __align__(16) short lsF[2][64 * BK];
  const int t = threadIdx.x;
  const int lane = t & 63, w = t >> 6;
  const int row16 = lane & 15, kgrp = lane >> 4;
  const int i0t = blockIdx.x * 64;
  const int kbeg = blockIdx.y * (NN / KSP);

  const float* gsrc[8];
  int sidx[8];
#pragma unroll
  for (int j = 0; j < 8; ++j) {
    const int v = t + 256 * j;
    const int row = v >> 5, col8 = v & 31;
    gsrc[j] = na + (size_t)(i0t + row) * NN + kbeg + col8 * 4;
    sidx[j] = row * BK + (((col8 >> 1) ^ (row & 15)) * 8) + (col8 & 1) * 4;
  }

  f32x4 GA[8], GB[8];
  f32x4 accS[4] = {};

#define ISSUE(G, step)                                                       \
  { _Pragma("unroll") for (int j = 0; j < 8; ++j)                            \
        G[j] = *reinterpret_cast<const f32x4*>(gsrc[j] + (step) * BK); }

#define WRITE(b, G)                                                          \
  { _Pragma("unroll") for (int j = 0; j < 8; ++j) {                          \
      s16x4 o;                                                               \
      _Pragma("unroll") for (int q = 0; q < 4; ++q)                          \
          o[q] = (G[j][q] > 0.f) ? (short)0x3F80 : (short)0;                 \
      *reinterpret_cast<s16x4*>(&lsF[b][sidx[j]]) = o;                       \
    } }

#define CONSUME(b, stp)                                                      \
  { _Pragma("unroll") for (int s = 0; s < 4; ++s) {                          \
      const int R = w * 16 + row16;                                          \
      const int slot = (s * 4 + kgrp) ^ row16;                               \
      const bf16x8 fS =                                                      \
          *reinterpret_cast<const bf16x8*>(&lsF[b][R * BK + slot * 8]);      \
      const size_t kg = (size_t)kbeg + (size_t)(stp)*BK + s * 32 + kgrp * 8; \
      _Pragma("unroll") for (int c = 0; c < 4; ++c) {                        \
        const bf16x8 B = *reinterpret_cast<const bf16x8*>(                   \
            ht + (size_t)(c * 16 + row16) * NN + kg);                        \
        accS[c] = __builtin_amdgcn_mfma_f32_16x16x32_bf16(fS, B, accS[c], 0, 0, 0); \
      }                                                                      \
    } }

  ISSUE(GA, 0);
  ISSUE(GB, 1);
  WRITE(0, GA);
  ISSUE(GA, 2);
  __syncthreads();
  for (int ss = 0; ss < NSTEP; ss += 2) {
    CONSUME(0, ss);
    __syncthreads();
    WRITE(1, GB);
    if (ss + 3 < NSTEP) ISSUE(GB, ss + 3);
    __syncthreads();
    CONSUME(1, ss + 1);
    __syncthreads();
    if (ss + 2 < NSTEP) {
      WRITE(0, GA);
      if (ss + 4 < NSTEP) ISSUE(GA, ss + 4);
    }
    __syncthreads();
  }
#undef ISSUE
#undef WRITE
#undef CONSUME

  const size_t base = (size_t)blockIdx.y * ((size_t)NN * HH);
#pragma unroll
  for (int c = 0; c < 4; ++c) {
#pragma unroll
    for (int r = 0; r < 4; ++r) {
      const int row = i0t + w * 16 + kgrp * 4 + r;
      const int col = c * 16 + row16;
      SpP[base + (size_t)row * HH + col] = accS[c][r];
    }
  }
}

// ---------------------------------------------------------------- fused epilogue: cgat + gruE + gruN + final
// 16 rows/block, 512 blocks; transposed weights -> coalesced lane reads.
template <int KSP>
__global__ __launch_bounds__(256) void k_epi(
    const float* __restrict__ h, const float* __restrict__ dn_g,
    const float* __restrict__ de_g, const float* __restrict__ Hb,
    const float* __restrict__ SpP, const float* __restrict__ TfP,
    const float* __restrict__ TpP, const float* __restrict__ cpP,
    const float* __restrict__ wa0, const float* __restrict__ wa1,
    const float* __restrict__ wihTe, const float* __restrict__ whhTe,
    const float* __restrict__ bihe, const float* __restrict__ bhhe,
    const float* __restrict__ WnT, const float* __restrict__ whhTn,
    const float* __restrict__ bihn, const float* __restrict__ bhhn,
    float* __restrict__ out) {
  __shared__ float xs[16][128];
  __shared__ float hs[16][64];
  __shared__ float us[16][64];
  __shared__ float eos[16][64];
  __shared__ float sHb[64], sw0[64], sw1[64];
  const int t = threadIdx.x;
  const int lane = t & 63, w = t >> 6;
  const int i0 = blockIdx.x * 16;
  const size_t SZ = (size_t)NN * HH;

  if (t < 64) {
    sHb[t] = Hb[t];
    sw0[t] = wa0[t];
    sw1[t] = wa1[t];
  }
  {
    const int row = t >> 4, c4 = (t & 15) * 4;
    *reinterpret_cast<float4*>(&hs[row][c4]) =
        *reinterpret_cast<const float4*>(&h[(size_t)(i0 + row) * 64 + c4]);
  }
  __syncthreads();

  // combine + analytic GAT, wave w handles rows w*4..w*4+3
  for (int rr = 0; rr < 4; ++rr) {
    const int row = w * 4 + rr;
    const size_t idx = (size_t)(i0 + row) * 64 + lane;
    float sp = 0.f, tf = 0.f, tp = 0.f;
#pragma unroll
    for (int s = 0; s < KSP; ++s) {
      sp += SpP[s * SZ + idx];
      tf += TfP[s * SZ + idx];
      tp += TpP[s * SZ + idx];
    }
    const float hv = hs[row][lane];
    const float dni = dn_g[i0 + row], dei = de_g[i0 + row];
    sp -= (dni > 0.f) ? hv : 0.f;
    tf -= dei * hv;
    tp -= fmaxf(dei, 0.f) * hv;
    const float sm = sHb[lane] - hv - sp;
    const float tm = tf - tp;
    float cp = 0.f;
#pragma unroll
    for (int s = 0; s < KSP; ++s) cp += cpP[s * NN + i0 + row];
    cp -= (dei > 0.f) ? 1.f : 0.f;
    float ep = sp * sw0[lane] + sm * sw1[lane];
    float em = sm * sw0[lane] + sp * sw1[lane];
#pragma unroll
    for (int off = 32; off >= 1; off >>= 1) {
      ep += __shfl_xor(ep, off);
      em += __shfl_xor(em, off);
    }
    ep = ep > 0.f ? ep : LALPHA * ep;
    em = em > 0.f ? em : LALPHA * em;
    const float cm = (float)(NN - 1) - cp;
    const float NEGI = -3.0e38f;
    const float m = fmaxf(cp > 0.f ? ep : NEGI, cm > 0.f ? em : NEGI);
    const float xp = (cp > 0.f) ? expf(ep - m) : 0.f;
    const float xm = (cm > 0.f) ? expf(em - m) : 0.f;
    const float den = cp * xp + cm * xm;
    const float inv = den > 0.f ? 1.f / den : 0.f;
    xs[row][lane] = sp;
    xs[row][64 + lane] = sm;
    us[row][lane] = xp * inv * tp + xm * inv * tm;  // U
  }
  __syncthreads();

  // GRU-edge
  {
    const int c = lane;
    float gi[3][4] = {}, gh[3][4] = {};
    for (int k = 0; k < 128; ++k) {
      const float wr = wihTe[k * 192 + c], wz = wihTe[k * 192 + 64 + c],
                  wn = wihTe[k * 192 + 128 + c];
#pragma unroll
      for (int rr = 0; rr < 4; ++rr) {
        const float x = xs[w * 4 + rr][k];
        gi[0][rr] += x * wr;
        gi[1][rr] += x * wz;
        gi[2][rr] += x * wn;
      }
    }
    for (int k = 0; k < 64; ++k) {
      const float ur = whhTe[k * 192 + c], uz = whhTe[k * 192 + 64 + c],
                  un = whhTe[k * 192 + 128 + c];
#pragma unroll
      for (int rr = 0; rr < 4; ++rr) {
        const float hv = hs[w * 4 + rr][k];
        gh[0][rr] += hv * ur;
        gh[1][rr] += hv * uz;
        gh[2][rr] += hv * un;
      }
    }
    const float br = bihe[c], bz = bihe[64 + c], bn = bihe[128 + c];
    const float dr = bhhe[c], dz = bhhe[64 + c], dnb = bhhe[128 + c];
#pragma unroll
    for (int rr = 0; rr < 4; ++rr) {
      const int row = w * 4 + rr;
      const float rg = 1.f / (1.f + expf(-(gi[0][rr] + br + gh[0][rr] + dr)));
      const float zg = 1.f / (1.f + expf(-(gi[1][rr] + bz + gh[1][rr] + dz)));
      const float ng = tanhf(gi[2][rr] + bn + rg * (gh[2][rr] + dnb));
      eos[row][c] = (1.f - zg) * ng + zg * hs[row][c];
    }
  }
  __syncthreads();

  // GRU-node (x = U via folded WnT) + final diag combine
  {
    const int c = lane;
    float gi[3][4] = {}, gh[3][4] = {};
    for (int k = 0; k < 64; ++k) {
      const float wr = WnT[k * 192 + c], wz = WnT[k * 192 + 64 + c],
                  wn = WnT[k * 192 + 128 + c];
      const float ur = whhTn[k * 192 + c], uz = whhTn[k * 192 + 64 + c],
                  un = whhTn[k * 192 + 128 + c];
#pragma unroll
      for (int rr = 0; rr < 4; ++rr) {
        const float x = us[w * 4 + rr][k], hv = hs[w * 4 + rr][k];
        gi[0][rr] += x * wr;
        gi[1][rr] += x * wz;
        gi[2][rr] += x * wn;
        gh[0][rr] += hv * ur;
        gh[1][rr] += hv * uz;
        gh[2][rr] += hv * un;
      }
    }
    const float br = bihn[c], bz = bihn[64 + c], bn = bihn[128 + c];
    const float dr = bhhn[c], dz = bhhn[64 + c], dnb = bhhn[128 + c];
#pragma unroll
    for (int rr = 0; rr < 4; ++rr) {
      const int row = w * 4 + rr;
      const float rg = 1.f / (1.f + expf(-(gi[0][rr] + br + gh[0][rr] + dr)));
      const float zg = 1.f / (1.f + expf(-(gi[1][rr] + bz + gh[1][rr] + dz)));
      const float ng = tanhf(gi[2][rr] + bn + rg * (gh[2][rr] + dnb));
      const float no = (1.f - zg) * ng + zg * hs[row][c];
      out[(size_t)(i0 + row) * 64 + c] =
          de_g[i0 + row] * eos[row][c] + dn_g[i0 + row] * no;
    }
  }
}

// ---------------------------------------------------------------- launch
template <int KSP>
static void launch_all(const float* h, const float* na, const float* ea,
                       const float* Wg, const float* ag, const float* wihe,
                       const float* whhe, const float* bihe, const float* bhhe,
                       const float* wihn, const float* whhn, const float* bihn,
                       const float* bhhn, float* out, float* ws,
                       hipStream_t stream) {
  const size_t SZ = (size_t)NN * HH;
  float* SpP = ws;
  float* TfP = ws + (size_t)KSP * SZ;
  float* TpP = ws + (size_t)2 * KSP * SZ;
  float* cpP = ws + (size_t)3 * KSP * SZ;
  float* dn = cpP + (size_t)KSP * NN;
  float* de = dn + NN;
  float* HbP = de + NN;          // 128*64
  float* Hb = HbP + 8192;        // 64
  float* wa0 = Hb + 64;
  float* wa1 = wa0 + 64;
  float* wihTe = wa1 + 64;       // 128*192
  float* whhTe = wihTe + 24576;  // 64*192
  float* WnT = whhTe + 12288;    // 64*192
  float* whhTn = WnT + 12288;    // 64*192
  unsigned short* ht = (unsigned short*)(whhTn + 12288);

  k_prep<<<NN / 64, 256, 0, stream>>>(h, na, ea, ht, dn, de, HbP);
  k_wprep<<<65, 256, 0, stream>>>(Wg, ag, wihe, whhe, wihn, whhn, HbP, Hb, wa0,
                                  wa1, wihTe, whhTe, WnT, whhTn);
  k_stageNA<KSP><<<dim3(NN / 64, KSP), 256, 0, stream>>>(na, ht, SpP);
  k_stageEA<KSP><<<dim3(NN / 64, KSP), 256, 0, stream>>>(ea, ht, TfP, TpP, cpP);
  k_epi<KSP><<<NN / 16, 256, 0, stream>>>(h, dn, de, Hb, SpP, TfP, TpP, cpP,
                                          wa0, wa1, wihTe, whhTe, bihe, bhhe,
                                          WnT, whhTn, bihn, bhhn, out);
}

extern "C" void kernel_launch(void* const* d_in, const int* in_sizes, int n_in,
                              void* d_out, int out_size, void* d_ws, size_t ws_size,
                              hipStream_t stream) {
  const float* h    = (const float*)d_in[0];
  const float* na   = (const float*)d_in[1];
  const float* ea   = (const float*)d_in[2];
  const float* Wg   = (const float*)d_in[3];
  const float* ag   = (const float*)d_in[4];
  const float* wihe = (const float*)d_in[5];
  const float* whhe = (const float*)d_in[6];
  const float* bihe = (const float*)d_in[7];
  const float* bhhe = (const float*)d_in[8];
  const float* wihn = (const float*)d_in[9];
  const float* whhn = (const float*)d_in[10];
  const float* bihn = (const float*)d_in[11];
  const float* bhhn = (const float*)d_in[12];
  float* out = (float*)d_out;
  float* ws  = (float*)d_ws;

  const size_t SZ = (size_t)NN * HH;
  auto need = [&](int ks) {
    return (3 * (size_t)ks * SZ + (size_t)ks * NN + 2 * NN + 8192 + 192 +
            24576 + 3 * 12288) * 4 + (size_t)NN * HH * 2;
  };
  if (ws_size >= need(4)) {
    launch_all<4>(h, na, ea, Wg, ag, wihe, whhe, bihe, bhhe, wihn, whhn,
                  bihn, bhhn, out, ws, stream);
  } else {
    launch_all<2>(h, na, ea, Wg, ag, wihe, whhe, bihe, bhhe, wihn, whhn,
                  bihn, bhhn, out, ws, stream);
  }
}

// Round 10
// 225.710 us; speedup vs baseline: 6.1664x; 1.2182x over previous
//
#include <hip/hip_runtime.h>

#define NN 8192
#define HH 64
constexpr float LALPHA = 0.2f;

typedef __attribute__((ext_vector_type(8))) short bf16x8;
typedef __attribute__((ext_vector_type(4))) float f32x4;

__device__ inline short f2bf(float f) {
  unsigned u = __builtin_bit_cast(unsigned, f);
  u += 0x7FFFu + ((u >> 16) & 1u);
  return (short)(u >> 16);
}

// ---------------------------------------------------------------- prep: ht transpose + diag + column-sum partials
__global__ __launch_bounds__(256) void k_prep(const float* __restrict__ h,
                                              const float* __restrict__ na,
                                              const float* __restrict__ ea,
                                              unsigned short* __restrict__ ht,
                                              float* __restrict__ dn,
                                              float* __restrict__ de,
                                              float* __restrict__ HbP) {
  __shared__ float tile[64][65];
  const int j0 = blockIdx.x * 64;
  for (int l = threadIdx.x; l < 64 * 64; l += 256) {
    int r = l >> 6, c = l & 63;
    tile[r][c] = h[(size_t)(j0 + r) * HH + c];
  }
  __syncthreads();
  for (int l = threadIdx.x; l < 64 * 64; l += 256) {
    int c = l >> 6, r = l & 63;
    ht[(size_t)c * NN + j0 + r] = (unsigned short)f2bf(tile[r][c]);
  }
  const int t = threadIdx.x;
  if (t < 64) {
    float s = 0.f;
    for (int r = 0; r < 64; ++r) s += tile[r][t];
    HbP[blockIdx.x * 64 + t] = s;
  } else if (t < 128) {
    int i = j0 + (t - 64);
    dn[i] = na[(size_t)i * NN + i];
    de[i] = ea[(size_t)i * NN + i];
  }
}

// ---------------------------------------------------------------- weight prep: transposes, Wn fold, wa, Hb
__global__ __launch_bounds__(256) void k_wprep(
    const float* __restrict__ W, const float* __restrict__ ag,
    const float* __restrict__ wihe, const float* __restrict__ whhe,
    const float* __restrict__ wihn, const float* __restrict__ whhn,
    const float* __restrict__ HbP, float* __restrict__ Hb,
    float* __restrict__ wa0, float* __restrict__ wa1,
    float* __restrict__ wihTe, float* __restrict__ whhTe,
    float* __restrict__ WnT, float* __restrict__ whhTn) {
  const int bid = blockIdx.x, t = threadIdx.x;
  if (bid == 64) {
    __shared__ float sW[64][64];
    __shared__ float sa[128];
    for (int l = t; l < 4096; l += 256) sW[l >> 6][l & 63] = W[l];
    if (t < 128) sa[t] = ag[t];
    __syncthreads();
    if (t < 64) {
      float s0 = 0.f, s1 = 0.f;
      for (int j = 0; j < 64; ++j) {
        s0 += sW[t][j] * sa[j];
        s1 += sW[t][j] * sa[64 + j];
      }
      wa0[t] = s0;
      wa1[t] = s1;
    } else if (t < 128) {
      int c = t - 64;
      float s = 0.f;
      for (int b = 0; b < 128; ++b) s += HbP[b * 64 + c];
      Hb[c] = s;
    }
    return;
  }
  for (int x = bid * 256 + t; x < 49152; x += 64 * 256) {
    if (x < 24576) {
      int k = x / 192, g = x % 192;
      wihTe[x] = wihe[g * 128 + k];
    } else if (x < 36864) {
      int o = x - 24576, k = o / 192, g = o % 192;
      whhTe[o] = whhe[g * 64 + k];
    } else {
      int o = x - 36864, k = o / 192, g = o % 192;
      whhTn[o] = whhn[g * 64 + k];
    }
  }
  if (bid < 48) {
    const int o = bid * 256 + t;
    const int k = o / 192, g = o % 192;
    float s = 0.f;
    for (int j = 0; j < 64; ++j) s += wihn[g * 64 + j] * W[k * 64 + j];
    WnT[o] = s;
  }
}

// ---------------------------------------------------------------- heavy masked matmuls via MFMA
// r7 register body + K-PHASE STAGGER: block (bx,ks) starts its k loop at
// iteration (bx & (ITERS-1)) and wraps, so concurrent blocks cover the full
// 32KB row span -> HBM channel spread instead of lockstep aliasing.
template <int KS>
__global__ __launch_bounds__(256, 4) void k_stageA(
    const float* __restrict__ na, const float* __restrict__ ea,
    const unsigned short* __restrict__ ht,
    float* __restrict__ SpP, float* __restrict__ TfP,
    float* __restrict__ TpP, float* __restrict__ cpP) {
  const int lane  = threadIdx.x & 63;
  const int wid   = threadIdx.x >> 6;
  const int row16 = lane & 15;
  const int kgrp  = lane >> 4;
  const int i0    = blockIdx.x * 64 + wid * 16;
  const int ks    = blockIdx.y;
  const int kbeg  = ks * (NN / KS);
  constexpr int ITERS = NN / KS / 32;
  const int start = blockIdx.x & (ITERS - 1);

  f32x4 accS[4] = {}, accF[4] = {}, accP[4] = {};
  float cnt = 0.f;

  const float* naRow = na + (size_t)(i0 + row16) * NN;
  const float* eaRow = ea + (size_t)(i0 + row16) * NN;

  for (int it = 0; it < ITERS; ++it) {
    int tt = start + it;
    if (tt >= ITERS) tt -= ITERS;
    const int kk = kbeg + tt * 32 + kgrp * 8;
    const float4 a0 = *reinterpret_cast<const float4*>(naRow + kk);
    const float4 a1 = *reinterpret_cast<const float4*>(naRow + kk + 4);
    const float4 e0 = *reinterpret_cast<const float4*>(eaRow + kk);
    const float4 e1 = *reinterpret_cast<const float4*>(eaRow + kk + 4);
    const float av[8] = {a0.x, a0.y, a0.z, a0.w, a1.x, a1.y, a1.z, a1.w};
    const float ev[8] = {e0.x, e0.y, e0.z, e0.w, e1.x, e1.y, e1.z, e1.w};
    bf16x8 fS, fF, fP;
#pragma unroll
    for (int q = 0; q < 8; ++q) {
      fS[q] = (av[q] > 0.f) ? (short)0x3F80 : (short)0;
      fF[q] = f2bf(ev[q]);
      fP[q] = f2bf(fmaxf(ev[q], 0.f));
      cnt += (ev[q] > 0.f) ? 1.f : 0.f;
    }
#pragma unroll
    for (int c = 0; c < 4; ++c) {
      const bf16x8 fB = *reinterpret_cast<const bf16x8*>(
          ht + (size_t)(c * 16 + row16) * NN + kk);
      accS[c] = __builtin_amdgcn_mfma_f32_16x16x32_bf16(fS, fB, accS[c], 0, 0, 0);
      accF[c] = __builtin_amdgcn_mfma_f32_16x16x32_bf16(fF, fB, accF[c], 0, 0, 0);
      accP[c] = __builtin_amdgcn_mfma_f32_16x16x32_bf16(fP, fB, accP[c], 0, 0, 0);
    }
  }
  cnt += __shfl_xor(cnt, 16);
  cnt += __shfl_xor(cnt, 32);
  if (lane < 16) cpP[ks * NN + i0 + lane] = cnt;

  const size_t base = (size_t)ks * ((size_t)NN * HH);
#pragma unroll
  for (int c = 0; c < 4; ++c) {
#pragma unroll
    for (int r = 0; r < 4; ++r) {
      const int row = i0 + kgrp * 4 + r;
      const int col = c * 16 + row16;
      const size_t idx = base + (size_t)row * HH + col;
      SpP[idx] = accS[c][r];
      TfP[idx] = accF[c][r];
      TpP[idx] = accP[c][r];
    }
  }
}

// ---------------------------------------------------------------- fused epilogue: cgat + gruE + gruN + final
template <int KSP>
__global__ __launch_bounds__(256) void k_epi(
    const float* __restrict__ h, const float* __restrict__ dn_g,
    const float* __restrict__ de_g, const float* __restrict__ Hb,
    const float* __restrict__ SpP, const float* __restrict__ TfP,
    const float* __restrict__ TpP, const float* __restrict__ cpP,
    const float* __restrict__ wa0, const float* __restrict__ wa1,
    const float* __restrict__ wihTe, const float* __restrict__ whhTe,
    const float* __restrict__ bihe, const float* __restrict__ bhhe,
    const float* __restrict__ WnT, const float* __restrict__ whhTn,
    const float* __restrict__ bihn, const float* __restrict__ bhhn,
    float* __restrict__ out) {
  __shared__ float xs[16][128];
  __shared__ float hs[16][64];
  __shared__ float us[16][64];
  __shared__ float eos[16][64];
  __shared__ float sHb[64], sw0[64], sw1[64];
  const int t = threadIdx.x;
  const int lane = t & 63, w = t >> 6;
  const int i0 = blockIdx.x * 16;
  const size_t SZ = (size_t)NN * HH;

  if (t < 64) {
    sHb[t] = Hb[t];
    sw0[t] = wa0[t];
    sw1[t] = wa1[t];
  }
  {
    const int row = t >> 4, c4 = (t & 15) * 4;
    *reinterpret_cast<float4*>(&hs[row][c4]) =
        *reinterpret_cast<const float4*>(&h[(size_t)(i0 + row) * 64 + c4]);
  }
  __syncthreads();

  for (int rr = 0; rr < 4; ++rr) {
    const int row = w * 4 + rr;
    const size_t idx = (size_t)(i0 + row) * 64 + lane;
    float sp = 0.f, tf = 0.f, tp = 0.f;
#pragma unroll
    for (int s = 0; s < KSP; ++s) {
      sp += SpP[s * SZ + idx];
      tf += TfP[s * SZ + idx];
      tp += TpP[s * SZ + idx];
    }
    const float hv = hs[row][lane];
    const float dni = dn_g[i0 + row], dei = de_g[i0 + row];
    sp -= (dni > 0.f) ? hv : 0.f;
    tf -= dei * hv;
    tp -= fmaxf(dei, 0.f) * hv;
    const float sm = sHb[lane] - hv - sp;
    const float tm = tf - tp;
    float cp = 0.f;
#pragma unroll
    for (int s = 0; s < KSP; ++s) cp += cpP[s * NN + i0 + row];
    cp -= (dei > 0.f) ? 1.f : 0.f;
    float ep = sp * sw0[lane] + sm * sw1[lane];
    float em = sm * sw0[lane] + sp * sw1[lane];
#pragma unroll
    for (int off = 32; off >= 1; off >>= 1) {
      ep += __shfl_xor(ep, off);
      em += __shfl_xor(em, off);
    }
    ep = ep > 0.f ? ep : LALPHA * ep;
    em = em > 0.f ? em : LALPHA * em;
    const float cm = (float)(NN - 1) - cp;
    const float NEGI = -3.0e38f;
    const float m = fmaxf(cp > 0.f ? ep : NEGI, cm > 0.f ? em : NEGI);
    const float xp = (cp > 0.f) ? expf(ep - m) : 0.f;
    const float xm = (cm > 0.f) ? expf(em - m) : 0.f;
    const float den = cp * xp + cm * xm;
    const float inv = den > 0.f ? 1.f / den : 0.f;
    xs[row][lane] = sp;
    xs[row][64 + lane] = sm;
    us[row][lane] = xp * inv * tp + xm * inv * tm;  // U
  }
  __syncthreads();

  // GRU-edge
  {
    const int c = lane;
    float gi[3][4] = {}, gh[3][4] = {};
    for (int k = 0; k < 128; ++k) {
      const float wr = wihTe[k * 192 + c], wz = wihTe[k * 192 + 64 + c],
                  wn = wihTe[k * 192 + 128 + c];
#pragma unroll
      for (int rr = 0; rr < 4; ++rr) {
        const float x = xs[w * 4 + rr][k];
        gi[0][rr] += x * wr;
        gi[1][rr] += x * wz;
        gi[2][rr] += x * wn;
      }
    }
    for (int k = 0; k < 64; ++k) {
      const float ur = whhTe[k * 192 + c], uz = whhTe[k * 192 + 64 + c],
                  un = whhTe[k * 192 + 128 + c];
#pragma unroll
      for (int rr = 0; rr < 4; ++rr) {
        const float hv = hs[w * 4 + rr][k];
        gh[0][rr] += hv * ur;
        gh[1][rr] += hv * uz;
        gh[2][rr] += hv * un;
      }
    }
    const float br = bihe[c], bz = bihe[64 + c], bn = bihe[128 + c];
    const float dr = bhhe[c], dz = bhhe[64 + c], dnb = bhhe[128 + c];
#pragma unroll
    for (int rr = 0; rr < 4; ++rr) {
      const int row = w * 4 + rr;
      const float rg = 1.f / (1.f + expf(-(gi[0][rr] + br + gh[0][rr] + dr)));
      const float zg = 1.f / (1.f + expf(-(gi[1][rr] + bz + gh[1][rr] + dz)));
      const float ng = tanhf(gi[2][rr] + bn + rg * (gh[2][rr] + dnb));
      eos[row][c] = (1.f - zg) * ng + zg * hs[row][c];
    }
  }
  __syncthreads();

  // GRU-node + final diag combine
  {
    const int c = lane;
    float gi[3][4] = {}, gh[3][4] = {};
    for (int k = 0; k < 64; ++k) {
      const float wr = WnT[k * 192 + c], wz = WnT[k * 192 + 64 + c],
                  wn = WnT[k * 192 + 128 + c];
      const float ur = whhTn[k * 192 + c], uz = whhTn[k * 192 + 64 + c],
                  un = whhTn[k * 192 + 128 + c];
#pragma unroll
      for (int rr = 0; rr < 4; ++rr) {
        const float x = us[w * 4 + rr][k], hv = hs[w * 4 + rr][k];
        gi[0][rr] += x * wr;
        gi[1][rr] += x * wz;
        gi[2][rr] += x * wn;
        gh[0][rr] += hv * ur;
        gh[1][rr] += hv * uz;
        gh[2][rr] += hv * un;
      }
    }
    const float br = bihn[c], bz = bihn[64 + c], bn = bihn[128 + c];
    const float dr = bhhn[c], dz = bhhn[64 + c], dnb = bhhn[128 + c];
#pragma unroll
    for (int rr = 0; rr < 4; ++rr) {
      const int row = w * 4 + rr;
      const float rg = 1.f / (1.f + expf(-(gi[0][rr] + br + gh[0][rr] + dr)));
      const float zg = 1.f / (1.f + expf(-(gi[1][rr] + bz + gh[1][rr] + dz)));
      const float ng = tanhf(gi[2][rr] + bn + rg * (gh[2][rr] + dnb));
      const float no = (1.f - zg) * ng + zg * hs[row][c];
      out[(size_t)(i0 + row) * 64 + c] =
          de_g[i0 + row] * eos[row][c] + dn_g[i0 + row] * no;
    }
  }
}

// ---------------------------------------------------------------- launch
template <int KSP>
static void launch_all(const float* h, const float* na, const float* ea,
                       const float* Wg, const float* ag, const float* wihe,
                       const float* whhe, const float* bihe, const float* bhhe,
                       const float* wihn, const float* whhn, const float* bihn,
                       const float* bhhn, float* out, float* ws,
                       hipStream_t stream) {
  const size_t SZ = (size_t)NN * HH;
  float* SpP = ws;
  float* TfP = ws + (size_t)KSP * SZ;
  float* TpP = ws + (size_t)2 * KSP * SZ;
  float* cpP = ws + (size_t)3 * KSP * SZ;
  float* dn = cpP + (size_t)KSP * NN;
  float* de = dn + NN;
  float* HbP = de + NN;          // 128*64
  float* Hb = HbP + 8192;        // 64
  float* wa0 = Hb + 64;
  float* wa1 = wa0 + 64;
  float* wihTe = wa1 + 64;       // 128*192
  float* whhTe = wihTe + 24576;  // 64*192
  float* WnT = whhTe + 12288;    // 64*192
  float* whhTn = WnT + 12288;    // 64*192
  unsigned short* ht = (unsigned short*)(whhTn + 12288);

  k_prep<<<NN / 64, 256, 0, stream>>>(h, na, ea, ht, dn, de, HbP);
  k_wprep<<<65, 256, 0, stream>>>(Wg, ag, wihe, whhe, wihn, whhn, HbP, Hb, wa0,
                                  wa1, wihTe, whhTe, WnT, whhTn);
  k_stageA<KSP><<<dim3(NN / 64, KSP), 256, 0, stream>>>(na, ea, ht, SpP, TfP,
                                                        TpP, cpP);
  k_epi<KSP><<<NN / 16, 256, 0, stream>>>(h, dn, de, Hb, SpP, TfP, TpP, cpP,
                                          wa0, wa1, wihTe, whhTe, bihe, bhhe,
                                          WnT, whhTn, bihn, bhhn, out);
}

extern "C" void kernel_launch(void* const* d_in, const int* in_sizes, int n_in,
                              void* d_out, int out_size, void* d_ws, size_t ws_size,
                              hipStream_t stream) {
  const float* h    = (const float*)d_in[0];
  const float* na   = (const float*)d_in[1];
  const float* ea   = (const float*)d_in[2];
  const float* Wg   = (const float*)d_in[3];
  const float* ag   = (const float*)d_in[4];
  const float* wihe = (const float*)d_in[5];
  const float* whhe = (const float*)d_in[6];
  const float* bihe = (const float*)d_in[7];
  const float* bhhe = (const float*)d_in[8];
  const float* wihn = (const float*)d_in[9];
  const float* whhn = (const float*)d_in[10];
  const float* bihn = (const float*)d_in[11];
  const float* bhhn = (const float*)d_in[12];
  float* out = (float*)d_out;
  float* ws  = (float*)d_ws;

  const size_t SZ = (size_t)NN * HH;
  auto need = [&](int ks) {
    return (3 * (size_t)ks * SZ + (size_t)ks * NN + 2 * NN + 8192 + 192 +
            24576 + 3 * 12288) * 4 + (size_t)NN * HH * 2;
  };
  if (ws_size >= need(8)) {
    launch_all<8>(h, na, ea, Wg, ag, wihe, whhe, bihe, bhhe, wihn, whhn,
                  bihn, bhhn, out, ws, stream);
  } else if (ws_size >= need(4)) {
    launch_all<4>(h, na, ea, Wg, ag, wihe, whhe, bihe, bhhe, wihn, whhn,
                  bihn, bhhn, out, ws, stream);
  } else {
    launch_all<2>(h, na, ea, Wg, ag, wihe, whhe, bihe, bhhe, wihn, whhn,
                  bihn, bhhn, out, ws, stream);
  }
}